// Round 2
// 920.641 us; speedup vs baseline: 1.1691x; 1.1691x over previous
//
#include <hip/hip_runtime.h>
#include <hip/hip_bf16.h>
#include <stdint.h>

#define NHQ   16
#define NHKV  8
#define DH    128
#define TSEQ  2048
#define HIDN  2048
#define IMID  8192
#define EPS   1e-6f
#define SCL   0.08838834764831845f  // 1/sqrt(128)

typedef __attribute__((ext_vector_type(8))) short short8;
typedef __attribute__((ext_vector_type(4))) short short4v;
typedef __attribute__((ext_vector_type(4))) float f32x4;
typedef unsigned int u32;
typedef unsigned short u16;

__device__ __forceinline__ float b2f(short s) {
  union { u32 u; float f; } cv; cv.u = ((u32)(u16)s) << 16; return cv.f;
}
__device__ __forceinline__ short f2b(float f) {
  union { float f; u32 u; } cv; cv.f = f;
  u32 u = cv.u;
  u32 r = u + 0x7FFFu + ((u >> 16) & 1u);
  return (short)(r >> 16);
}

// async 16B global -> LDS (dest = wave-uniform base + lane*16)  [m97-verified]
__device__ __forceinline__ void gll16(const void* g, void* l) {
  __builtin_amdgcn_global_load_lds(
      (const __attribute__((address_space(1))) u32*)g,
      (__attribute__((address_space(3))) u32*)l, 16, 0, 0);
}

// ---------------------------------------------------------------------------
// fp32 -> bf16 weight convert, 8 elems/thread
// ---------------------------------------------------------------------------
__global__ __launch_bounds__(256)
void cvt_f2b(const float* __restrict__ in, short* __restrict__ out)
{
  const size_t i = ((size_t)blockIdx.x*256 + threadIdx.x)*8;
  f32x4 a0 = *(const f32x4*)(in + i);
  f32x4 a1 = *(const f32x4*)(in + i + 4);
  short8 y;
  #pragma unroll
  for (int j = 0; j < 4; ++j) { y[j] = f2b(a0[j]); y[j+4] = f2b(a1[j]); }
  *(short8*)(out + i) = y;
}

// ---------------------------------------------------------------------------
// C = A @ B^T.  A: bf16 (M,K) lda.  B: bf16 (N,K) if !BF32 else fp32 (N,K),
// converted during staging.  fp32 accum.  128x128 tile, BK=64, 256 thr.
// (kept for the small QKV / wo GEMMs -- verified structure)
// ---------------------------------------------------------------------------
template<int EPI, bool BF32>
__global__ __launch_bounds__(256)
void gemm_bt(const short* __restrict__ A, int lda,
             const void* __restrict__ Bp,
             const void* __restrict__ RES,
             void* __restrict__ C, int N, int K)
{
  __shared__ __attribute__((aligned(16))) short As[128*64];
  __shared__ __attribute__((aligned(16))) short Bs[128*64];

  const int tid = threadIdx.x;
  const int wv = tid >> 6, ln = tid & 63;
  const int wm = wv >> 1, wn = wv & 1;
  const int l15 = ln & 15, quad = ln >> 4;
  const int bm0 = blockIdx.x * 128, bn0 = blockIdx.y * 128;

  f32x4 acc[4][4];
  #pragma unroll
  for (int i = 0; i < 4; ++i)
    #pragma unroll
    for (int j = 0; j < 4; ++j) acc[i][j] = (f32x4){0.f,0.f,0.f,0.f};

  const int srow = wv*32 + (ln >> 3);  // staging row base (+= i*8)
  const int schk = ln & 7;             // physical chunk this lane fills
  const int brow = tid >> 4;           // fp32-B staging coords
  const int bgrp = tid & 15;

  for (int kt = 0; kt < K; kt += 64) {
    #pragma unroll
    for (int i = 0; i < 4; ++i) {
      const int r = srow + i*8;
      const int g = schk ^ (r & 7);
      gll16(A + (size_t)(bm0 + r)*lda + kt + g*8,
            (char*)As + (wv*32 + i*8)*128);
      if (!BF32)
        gll16((const short*)Bp + (size_t)(bn0 + r)*K + kt + g*8,
              (char*)Bs + (wv*32 + i*8)*128);
    }
    if (BF32) {
      #pragma unroll
      for (int p = 0; p < 8; ++p) {
        const int r = p*16 + brow;
        f32x4 w4 = *(const f32x4*)((const float*)Bp + (size_t)(bn0 + r)*K + kt + bgrp*4);
        short4v s4;
        #pragma unroll
        for (int j = 0; j < 4; ++j) s4[j] = f2b(w4[j]);
        *(short4v*)(Bs + r*64 + (((bgrp >> 1) ^ (r & 7))*8) + (bgrp & 1)*4) = s4;
      }
    }
    __syncthreads();

    #pragma unroll
    for (int ks = 0; ks < 2; ++ks) {
      short8 af[4], bfr[4];
      #pragma unroll
      for (int mi = 0; mi < 4; ++mi) {
        const int r = wm*64 + mi*16 + l15;
        const int p = (quad + ks*4) ^ (r & 7);
        af[mi] = *(const short8*)(As + r*64 + p*8);
      }
      #pragma unroll
      for (int ni = 0; ni < 4; ++ni) {
        const int r = wn*64 + ni*16 + l15;
        const int p = (quad + ks*4) ^ (r & 7);
        bfr[ni] = *(const short8*)(Bs + r*64 + p*8);
      }
      #pragma unroll
      for (int mi = 0; mi < 4; ++mi)
        #pragma unroll
        for (int ni = 0; ni < 4; ++ni)
          acc[mi][ni] = __builtin_amdgcn_mfma_f32_16x16x32_bf16(
              af[mi], bfr[ni], acc[mi][ni], 0, 0, 0);
    }
    __syncthreads();
  }

  #pragma unroll
  for (int mi = 0; mi < 4; ++mi) {
    #pragma unroll
    for (int reg = 0; reg < 4; ++reg) {
      const int row = bm0 + wm*64 + mi*16 + quad*4 + reg;
      #pragma unroll
      for (int ni = 0; ni < 4; ++ni) {
        const int col = bn0 + wn*64 + ni*16 + l15;
        const size_t off = (size_t)row*N + col;
        const float v = acc[mi][ni][reg];
        if (EPI == 0)      ((short*)C)[off] = f2b(v);
        else if (EPI == 1) ((float*)C)[off] = b2f(((const short*)RES)[off]) + v;
        else               ((float*)C)[off] = ((const float*)RES)[off] + v;
      }
    }
  }
}

// ---------------------------------------------------------------------------
// 256x256 8-phase pipelined GEMM (T1+T2+T3+T4+T5).  C = A @ B^T, bf16 in,
// fp32 accum.  A: (M,K) lda.  B: (N,K) ldb.  512 thr = 8 waves (2M x 4N),
// per-wave output 128x64.  BK=64; 2 K-tiles double-buffered in 128 KiB LDS,
// each tile split into 2 halves (A0,A1,B0,B1 regions of 16 KiB).
// Per phase: ds_read one quadrant's frags | stage ONE half-tile (2x gll16)
// | s_barrier | lgkmcnt(0) | setprio(1) 16x MFMA setprio(0) | s_barrier.
// Counted s_waitcnt vmcnt(4) ONLY at phases 4 and 8 -- prefetch loads stay
// in flight across barriers (no vmcnt(0) drain anywhere in the main loop).
// Stage schedule (iter computes tiles u=2i [slot0, ph1-4], u+1 [slot1, ph5-8]):
//   ph1: A0->s1(u+1)  ph2: A1->s1(u+1)  ph3: B0->s0(u+2)  ph4: B1->s0(u+2)
//   ph5: A0->s0(u+2)  ph6: A1->s0(u+2)  ph7: B0->s1(u+3)  ph8: B1->s1(u+3)
// Every staged region's last reads finish >=1 barrier before the stage issues,
// and every region's first re-read is gated behind a vmcnt(4) that retires it
// (invariant: each VMC4 retires all but the 2 newest STG-pairs; every
// stage->first-reread distance is >=2 STG-pairs with a VMC4 between).
// sched_barrier(0) after every s_barrier: s_barrier is IntrNoMem in LLVM, so
// without the pin the scheduler may hoist post-barrier ds_reads above it
// (m152 race class).  LDS chunk-XOR swizzle (phys 16B chunk p of row r holds
// logical p^(r&7)): conflict-free ds_read_b128 via pre-swizzled global src.
// EPI: 0 = bf16 store; 3 = fp32 atomicAdd (split-K over blockIdx.z).
// Requires: M%256==0, N%256==0, Ko%128==0 (NT even).
// ---------------------------------------------------------------------------
#define BAR256()   do { __builtin_amdgcn_s_barrier();                      \
                        __builtin_amdgcn_sched_barrier(0); } while (0)
#define LGKM0()    do { asm volatile("s_waitcnt lgkmcnt(0)" ::: "memory"); \
                        __builtin_amdgcn_sched_barrier(0); } while (0)
#define VMC4()     do { asm volatile("s_waitcnt vmcnt(4)" ::: "memory");   \
                        __builtin_amdgcn_sched_barrier(0); } while (0)

template<int EPI>
__global__ __launch_bounds__(512, 2)
void gemm256(const short* __restrict__ A, int lda,
             const short* __restrict__ B, int ldb,
             void* __restrict__ C, int N, int Ko)
{
  __shared__ __attribute__((aligned(16))) char L[131072];
  // A slot s half h: (s*2+h)*16384   B: +65536

  const int tid = threadIdx.x;
  const int wv = tid >> 6, ln = tid & 63;
  const int wm = wv >> 2, wn = wv & 3;
  const int l15 = ln & 15, quad = ln >> 4;

  // XCD-aware bijective swizzle (nwg % 8 == 0 for all our grids)
  int bx, by;
  {
    const int nwg  = gridDim.x * gridDim.y;
    const int orig = blockIdx.y * gridDim.x + blockIdx.x;
    const int wg   = (orig & 7) * (nwg >> 3) + (orig >> 3);
    bx = wg % gridDim.x;
    by = wg / gridDim.x;
  }
  const int bm0 = bx * 256, bn0 = by * 256;
  const int k0  = blockIdx.z * Ko;

  // staging constants: thread fills row (i*64 + wv*8 + (ln>>3)), phys chunk ln&7;
  // logical chunk g = (ln&7) ^ (row&7), and row&7 == (ln>>3)&7 for all i.
  const int srow = wv*8 + (ln >> 3);
  const int g8   = ((ln & 7) ^ ((ln >> 3) & 7)) * 8;
  const short* Ab = A + (size_t)bm0 * lda + k0 + g8;
  const short* Bb = B + (size_t)bn0 * ldb + k0 + g8;

  // LDS-read constants (phys chunk = (ks*4+quad) ^ (row&7), row&7 == l15&7)
  const int aro = l15 * 128;
  const int p0  = ((quad    ) ^ (l15 & 7)) * 16;
  const int p1  = ((quad + 4) ^ (l15 & 7)) * 16;

  f32x4 acc[8][4];
  #pragma unroll
  for (int i = 0; i < 8; ++i)
    #pragma unroll
    for (int j = 0; j < 4; ++j) acc[i][j] = (f32x4){0.f,0.f,0.f,0.f};

  short8 af[4][2], bf0[2][2], bf1[2][2];

  const int NT = Ko >> 6;   // K-tiles (even)
  const int NI = NT >> 1;

#define STG(base, ld, s, h, t, isB)                                          \
  { char* r_ = L + (isB)*65536 + ((s)*2 + (h))*16384 + wv*1024;              \
    _Pragma("unroll")                                                        \
    for (int i_ = 0; i_ < 2; ++i_)                                           \
      gll16(base + (size_t)((h)*128 + i_*64 + srow)*(ld) + (size_t)(t)*64,   \
            r_ + i_*8192); }

#define LD_A(s, mh)                                                          \
  { const char* a_ = L + ((s)*2 + wm)*16384 + (mh)*8192 + aro;               \
    _Pragma("unroll")                                                        \
    for (int m_ = 0; m_ < 4; ++m_) {                                         \
      af[m_][0] = *(const short8*)(a_ + m_*2048 + p0);                       \
      af[m_][1] = *(const short8*)(a_ + m_*2048 + p1);                       \
    } }

#define LD_B(s, nh, bfv)                                                     \
  { const char* b_ = L + 65536 + ((s)*2 + (wn>>1))*16384 + (wn&1)*8192       \
                     + (nh)*4096 + aro;                                      \
    _Pragma("unroll")                                                        \
    for (int n_ = 0; n_ < 2; ++n_) {                                         \
      bfv[n_][0] = *(const short8*)(b_ + n_*2048 + p0);                      \
      bfv[n_][1] = *(const short8*)(b_ + n_*2048 + p1);                      \
    } }

#define MM_Q(mh, nh, bfv)                                                    \
  { __builtin_amdgcn_s_setprio(1);                                           \
    _Pragma("unroll")                                                        \
    for (int m_ = 0; m_ < 4; ++m_)                                           \
      _Pragma("unroll")                                                      \
      for (int n_ = 0; n_ < 2; ++n_) {                                       \
        acc[(mh)*4+m_][(nh)*2+n_] = __builtin_amdgcn_mfma_f32_16x16x32_bf16( \
            af[m_][0], bfv[n_][0], acc[(mh)*4+m_][(nh)*2+n_], 0, 0, 0);      \
        acc[(mh)*4+m_][(nh)*2+n_] = __builtin_amdgcn_mfma_f32_16x16x32_bf16( \
            af[m_][1], bfv[n_][1], acc[(mh)*4+m_][(nh)*2+n_], 0, 0, 0);      \
      }                                                                      \
    __builtin_amdgcn_s_setprio(0); }

  // prologue: tile0 -> slot0 (all 4 halves); tile1 B halves -> slot1.
  // 12 loads/wave issued; vmcnt(4) retires the 8 of tile0, leaves tile1-B (4).
  STG(Ab, lda, 0,0, 0, 0); STG(Ab, lda, 0,1, 0, 0);
  STG(Bb, ldb, 0,0, 0, 1); STG(Bb, ldb, 0,1, 0, 1);
  STG(Bb, ldb, 1,0, 1, 1); STG(Bb, ldb, 1,1, 1, 1);
  VMC4();
  BAR256();

  for (int it = 0; it < NI; ++it) {
    const int u   = it*2;
    const int tA1 = u + 1;
    const int t2  = (u+2 < NT) ? u+2 : NT-1;   // clamped: keeps vmcnt counting
    const int t3  = (u+3 < NT) ? u+3 : NT-1;   // exact; garbage data never read

    // ph1: Q(m0,n0) slot0 | stage A0->s1 (u+1)
    LD_A(0,0); LD_B(0,0,bf0);
    STG(Ab, lda, 1,0, tA1, 0);
    BAR256(); LGKM0();
    MM_Q(0,0,bf0);
    BAR256();
    // ph2: Q(m0,n1) slot0 | stage A1->s1 (u+1)
    LD_B(0,1,bf1);
    STG(Ab, lda, 1,1, tA1, 0);
    BAR256(); LGKM0();
    MM_Q(0,1,bf1);
    BAR256();
    // ph3: Q(m1,n0) slot0 | stage B0->s0 (u+2)
    LD_A(0,1);
    STG(Bb, ldb, 0,0, t2, 1);
    BAR256(); LGKM0();
    MM_Q(1,0,bf0);
    BAR256();
    // ph4: Q(m1,n1) slot0 | stage B1->s0 (u+2) | vmcnt(4)
    STG(Bb, ldb, 0,1, t2, 1);
    BAR256(); LGKM0();
    MM_Q(1,1,bf1);
    VMC4();
    BAR256();
    // ph5: Q(m0,n0) slot1 | stage A0->s0 (u+2)
    LD_A(1,0); LD_B(1,0,bf0);
    STG(Ab, lda, 0,0, t2, 0);
    BAR256(); LGKM0();
    MM_Q(0,0,bf0);
    BAR256();
    // ph6: Q(m0,n1) slot1 | stage A1->s0 (u+2)
    LD_B(1,1,bf1);
    STG(Ab, lda, 0,1, t2, 0);
    BAR256(); LGKM0();
    MM_Q(0,1,bf1);
    BAR256();
    // ph7: Q(m1,n0) slot1 | stage B0->s1 (u+3)
    LD_A(1,1);
    STG(Bb, ldb, 1,0, t3, 1);
    BAR256(); LGKM0();
    MM_Q(1,0,bf0);
    BAR256();
    // ph8: Q(m1,n1) slot1 | stage B1->s1 (u+3) | vmcnt(4)
    STG(Bb, ldb, 1,1, t3, 1);
    BAR256(); LGKM0();
    MM_Q(1,1,bf1);
    VMC4();
    BAR256();
  }

  #pragma unroll
  for (int mi = 0; mi < 8; ++mi) {
    #pragma unroll
    for (int reg = 0; reg < 4; ++reg) {
      const int row = bm0 + wm*128 + mi*16 + quad*4 + reg;
      #pragma unroll
      for (int ni = 0; ni < 4; ++ni) {
        const int col = bn0 + wn*64 + ni*16 + l15;
        const size_t off = (size_t)row*N + col;
        const float v = acc[mi][ni][reg];
        if (EPI == 0) ((short*)C)[off] = f2b(v);
        else          atomicAdd((float*)C + off, v);
      }
    }
  }
#undef STG
#undef LD_A
#undef LD_B
#undef MM_Q
}

// ---------------------------------------------------------------------------
// fp32 (rows_in, cols_in) -> bf16 (cols_in, rows_in)
// ---------------------------------------------------------------------------
__global__ __launch_bounds__(256)
void transpose_f2b(const float* __restrict__ in, short* __restrict__ out,
                   int rows_in, int cols_in)
{
  __shared__ float tile[64][65];
  const int c0 = blockIdx.x*64, r0 = blockIdx.y*64;
  const int tx = threadIdx.x & 63, ty = threadIdx.x >> 6;
  #pragma unroll
  for (int i = 0; i < 16; ++i) {
    const int r = ty + i*4;
    tile[r][tx] = in[(size_t)(r0+r)*cols_in + c0 + tx];
  }
  __syncthreads();
  #pragma unroll
  for (int i = 0; i < 16; ++i) {
    const int r = ty + i*4;
    out[(size_t)(c0+r)*rows_in + r0 + tx] = f2b(tile[tx][r]);
  }
}

// fp32 (rows_in, cols_in) -> fp32 (cols_in, rows_in)
__global__ __launch_bounds__(256)
void transpose_f2f(const float* __restrict__ in, float* __restrict__ out,
                   int rows_in, int cols_in)
{
  __shared__ float tile[64][65];
  const int c0 = blockIdx.x*64, r0 = blockIdx.y*64;
  const int tx = threadIdx.x & 63, ty = threadIdx.x >> 6;
  #pragma unroll
  for (int i = 0; i < 16; ++i) {
    const int r = ty + i*4;
    tile[r][tx] = in[(size_t)(r0+r)*cols_in + c0 + tx];
  }
  __syncthreads();
  #pragma unroll
  for (int i = 0; i < 16; ++i) {
    const int r = ty + i*4;
    out[(size_t)(c0+r)*rows_in + r0 + tx] = tile[tx][r];
  }
}

// ---------------------------------------------------------------------------
// row RMSNorm over HID=2048. X bf16, W fp32, Y bf16.
// ---------------------------------------------------------------------------
__global__ __launch_bounds__(256)
void rmsnorm_b(const short* __restrict__ X, const float* __restrict__ W,
               short* __restrict__ Y)
{
  const int row = blockIdx.x, tid = threadIdx.x;
  const int wv = tid >> 6, ln = tid & 63;
  const size_t base = (size_t)row*HIDN + tid*8;
  short8 xv = *(const short8*)(X + base);
  float x[8];
  #pragma unroll
  for (int j = 0; j < 8; ++j) x[j] = b2f(xv[j]);
  float s = 0.f;
  #pragma unroll
  for (int j = 0; j < 8; ++j) s += x[j]*x[j];
  #pragma unroll
  for (int off = 32; off; off >>= 1) s += __shfl_xor(s, off, 64);
  __shared__ float red[4];
  if (ln == 0) red[wv] = s;
  __syncthreads();
  const float tot = red[0]+red[1]+red[2]+red[3];
  const float r = rsqrtf(tot*(1.0f/HIDN) + EPS);
  f32x4 w0 = *(const f32x4*)(W + tid*8);
  f32x4 w1 = *(const f32x4*)(W + tid*8 + 4);
  short8 y;
  #pragma unroll
  for (int j = 0; j < 4; ++j) y[j]   = f2b(x[j]*r*w0[j]);
  #pragma unroll
  for (int j = 0; j < 4; ++j) y[j+4] = f2b(x[j+4]*r*w1[j]);
  *(short8*)(Y + base) = y;
}

// X fp32, W fp32, Y bf16
__global__ __launch_bounds__(256)
void rmsnorm_f(const float* __restrict__ X, const float* __restrict__ W,
               short* __restrict__ Y)
{
  const int row = blockIdx.x, tid = threadIdx.x;
  const int wv = tid >> 6, ln = tid & 63;
  const size_t base = (size_t)row*HIDN + tid*8;
  f32x4 a0 = *(const f32x4*)(X + base);
  f32x4 a1 = *(const f32x4*)(X + base + 4);
  float x[8] = {a0[0],a0[1],a0[2],a0[3],a1[0],a1[1],a1[2],a1[3]};
  float s = 0.f;
  #pragma unroll
  for (int j = 0; j < 8; ++j) s += x[j]*x[j];
  #pragma unroll
  for (int off = 32; off; off >>= 1) s += __shfl_xor(s, off, 64);
  __shared__ float red[4];
  if (ln == 0) red[wv] = s;
  __syncthreads();
  const float tot = red[0]+red[1]+red[2]+red[3];
  const float r = rsqrtf(tot*(1.0f/HIDN) + EPS);
  f32x4 w0 = *(const f32x4*)(W + tid*8);
  f32x4 w1 = *(const f32x4*)(W + tid*8 + 4);
  short8 y;
  #pragma unroll
  for (int j = 0; j < 4; ++j) y[j]   = f2b(x[j]*r*w0[j]);
  #pragma unroll
  for (int j = 0; j < 4; ++j) y[j+4] = f2b(x[j+4]*r*w1[j]);
  *(short8*)(Y + base) = y;
}

// ---------------------------------------------------------------------------
// fused per-head RMSNorm (D=128) + RoPE, in-place on bf16 q/k.
// ---------------------------------------------------------------------------
__global__ __launch_bounds__(64)
void qk_rms_rope(short* __restrict__ Qb, short* __restrict__ Kb,
                 const float* __restrict__ cosb, const float* __restrict__ sinb,
                 const float* __restrict__ qw, const float* __restrict__ kw)
{
  const int b = blockIdx.x;
  const int hi = b % (NHQ + NHKV);
  const int t  = b / (NHQ + NHKV);
  const int ln = threadIdx.x;
  short* row; const float* w;
  if (hi < NHQ) { row = Qb + (size_t)t*(NHQ*DH) + hi*DH; w = qw; }
  else          { row = Kb + (size_t)t*(NHKV*DH) + (hi-NHQ)*DH; w = kw; }
  float x0 = b2f(row[ln]), x1 = b2f(row[ln+64]);
  float s = x0*x0 + x1*x1;
  #pragma unroll
  for (int off = 32; off; off >>= 1) s += __shfl_xor(s, off, 64);
  const float r = rsqrtf(s*(1.0f/DH) + EPS);
  const float n0 = x0*r*w[ln];
  const float n1 = x1*r*w[ln+64];
  const float* cr = cosb + (size_t)t*DH;
  const float* sr = sinb + (size_t)t*DH;
  const float c0 = cr[ln], c1 = cr[ln+64];
  const float s0 = sr[ln], s1 = sr[ln+64];
  row[ln]    = f2b(n0*c0 - n1*s0);
  row[ln+64] = f2b(n1*c1 + n0*s1);
}

// ---------------------------------------------------------------------------
// causal flash attention, 16x16x32 MFMA (unchanged this round).
// ---------------------------------------------------------------------------
__global__ __launch_bounds__(256)
void flash_attn(const short* __restrict__ Q, const short* __restrict__ Kb,
                const short* __restrict__ Vb, short* __restrict__ O)
{
  __shared__ __attribute__((aligned(16))) short Ks[64*128];  // [s][d]
  __shared__ __attribute__((aligned(16))) short Vt[128*64];  // [d][s]
  __shared__ __attribute__((aligned(16))) short Ps[4*16*64]; // per-wave [m][s]

  const int tid = threadIdx.x, wv = tid >> 6, ln = tid & 63;
  const int l15 = ln & 15, quad = ln >> 4;
  const int hh = blockIdx.y, kvh = hh >> 1;
  const int m0 = blockIdx.x * 64;
  const int qm0 = m0 + wv*16;

  short8 qf[4];
  {
    const short* qb = Q + (size_t)(qm0 + l15)*(NHQ*DH) + hh*DH + quad*8;
    #pragma unroll
    for (int ks = 0; ks < 4; ++ks) qf[ks] = *(const short8*)(qb + ks*32);
  }

  f32x4 oa[8];
  #pragma unroll
  for (int i = 0; i < 8; ++i) oa[i] = (f32x4){0.f,0.f,0.f,0.f};
  float m_r[4] = {-1e30f,-1e30f,-1e30f,-1e30f};
  float l_r[4] = {0.f,0.f,0.f,0.f};

  const int ntile = blockIdx.x + 1;
  for (int st = 0; st < ntile; ++st) {
    const int s0 = st*64;
    __syncthreads();

    #pragma unroll
    for (int it = 0; it < 4; ++it) {
      const int r = (wv*4 + it)*4 + quad;
      gll16(Kb + (size_t)(s0 + r)*(NHKV*DH) + kvh*DH + l15*8,
            (char*)Ks + (wv*4 + it)*1024);
    }
    {
      const int d = tid & 127, sh = tid >> 7;
      #pragma unroll
      for (int cb = 0; cb < 4; ++cb) {
        short8 t8;
        #pragma unroll
        for (int j = 0; j < 8; ++j)
          t8[j] = Vb[(size_t)(s0 + sh*32 + cb*8 + j)*(NHKV*DH) + kvh*DH + d];
        *(short8*)(Vt + d*64 + (sh*4 + cb)*8) = t8;
      }
    }
    __syncthreads();

    f32x4 sc[4];
    #pragma unroll
    for (int ci = 0; ci < 4; ++ci) {
      f32x4 a = (f32x4){0.f,0.f,0.f,0.f};
      #pragma unroll
      for (int ks = 0; ks < 4; ++ks) {
        const int r = ci*16 + l15;
        short8 kf = *(const short8*)(Ks + r*128 + (quad + ks*4)*8);
        a = __builtin_amdgcn_mfma_f32_16x16x32_bf16(qf[ks], kf, a, 0, 0, 0);
      }
      sc[ci] = a;
    }

    float alpha[4];
    #pragma unroll
    for (int reg = 0; reg < 4; ++reg) {
      const int grow = qm0 + quad*4 + reg;
      float rmax = -1e30f;
      #pragma unroll
      for (int ci = 0; ci < 4; ++ci) {
        float v = sc[ci][reg]*SCL;
        const int gs = s0 + ci*16 + l15;
        v = (gs <= grow) ? v : -1e30f;
        sc[ci][reg] = v;
        rmax = fmaxf(rmax, v);
      }
      #pragma unroll
      for (int off = 1; off < 16; off <<= 1)
        rmax = fmaxf(rmax, __shfl_xor(rmax, off, 64));
      const float mn = fmaxf(m_r[reg], rmax);
      alpha[reg] = __expf(m_r[reg] - mn);
      m_r[reg] = mn;
      float rsum = 0.f;
      #pragma unroll
      for (int ci = 0; ci < 4; ++ci) {
        const float p = __expf(sc[ci][reg] - mn);
        sc[ci][reg] = p;
        rsum += p;
      }
      #pragma unroll
      for (int off = 1; off < 16; off <<= 1)
        rsum += __shfl_xor(rsum, off, 64);
      l_r[reg] = l_r[reg]*alpha[reg] + rsum;
    }
    #pragma unroll
    for (int ni = 0; ni < 8; ++ni)
      #pragma unroll
      for (int reg = 0; reg < 4; ++reg) oa[ni][reg] *= alpha[reg];

    #pragma unroll
    for (int ci = 0; ci < 4; ++ci)
      #pragma unroll
      for (int reg = 0; reg < 4; ++reg)
        Ps[wv*1024 + (quad*4 + reg)*64 + ci*16 + l15] = f2b(sc[ci][reg]);

    __syncthreads();

    #pragma unroll
    for (int ks = 0; ks < 2; ++ks) {
      const int gp = quad + ks*4;
      short8 pf = *(const short8*)(Ps + wv*1024 + l15*64 + gp*8);
      #pragma unroll
      for (int ni = 0; ni < 8; ++ni) {
        const int d = ni*16 + l15;
        short8 vf = *(const short8*)(Vt + d*64 + gp*8);
        oa[ni] = __builtin_amdgcn_mfma_f32_16x16x32_bf16(pf, vf, oa[ni], 0, 0, 0);
      }
    }
  }

  #pragma unroll
  for (int reg = 0; reg < 4; ++reg) {
    const float inv = 1.0f / l_r[reg];
    const int row = qm0 + quad*4 + reg;
    #pragma unroll
    for (int ni = 0; ni < 8; ++ni)
      O[(size_t)row*(NHQ*DH) + hh*DH + ni*16 + l15] = f2b(oa[ni][reg]*inv);
  }
}

// ---------------------------------------------------------------------------
// gate half of gu (T, 2I)  <-  silu(gate) * up, in place (bf16)
// ---------------------------------------------------------------------------
__global__ __launch_bounds__(256)
void silu_mul(short* __restrict__ gu)
{
  const size_t idx = ((size_t)blockIdx.x*256 + threadIdx.x)*8;
  const size_t t = idx / IMID;
  const size_t i = idx % IMID;
  short* gp = gu + t*(2*IMID) + i;
  short8 g8 = *(const short8*)gp;
  short8 u8 = *(const short8*)(gp + IMID);
  short8 o;
  #pragma unroll
  for (int j = 0; j < 8; ++j) {
    const float g = b2f(g8[j]);
    const float u = b2f(u8[j]);
    const float sl = g / (1.f + __expf(-g));
    o[j] = f2b(sl*u);
  }
  *(short8*)gp = o;
}

// ---------------------------------------------------------------------------
extern "C" void kernel_launch(void* const* d_in, const int* in_sizes, int n_in,
                              void* d_out, int out_size, void* d_ws, size_t ws_size,
                              hipStream_t stream)
{
  const float* hc   = (const float*)d_in[0];
  const float* cosb = (const float*)d_in[1];
  const float* sinb = (const float*)d_in[2];
  const float* wq   = (const float*)d_in[5];
  const float* wk   = (const float*)d_in[6];
  const float* wvp  = (const float*)d_in[7];
  const float* wo   = (const float*)d_in[8];
  const float* wgu  = (const float*)d_in[9];
  const float* wdn  = (const float*)d_in[10];
  const float* iln  = (const float*)d_in[11];
  const float* pln  = (const float*)d_in[12];
  const float* qnw  = (const float*)d_in[13];
  const float* knw  = (const float*)d_in[14];

  // workspace map (192 MB peak):
  //  wgu_b 0-64 | wq_b 64-72 | wk_b 72-76 | wv_b 76-80 | wo_b 80-88
  //  xT 88-96 | h 96-104 | q 104-112 | k 112-116 | v 116-120 | ao 120-128
  //  hid (fp32) 104-120 (over q/k/v, dead after flash)
  //  h2 120-128 (over ao, dead after wo-gemm) | gu 128-192
  //  wdn_b 64-96 (over wq_b..xT, all dead after wo-gemm)
  char* ws = (char*)d_ws;
  short* wgu_b = (short*)(ws);
  short* wq_b  = (short*)(ws + ((size_t)64 << 20));
  short* wk_b  = (short*)(ws + ((size_t)72 << 20));
  short* wv_b  = (short*)(ws + ((size_t)76 << 20));
  short* wo_b  = (short*)(ws + ((size_t)80 << 20));
  short* xT    = (short*)(ws + ((size_t)88 << 20));
  short* h     = (short*)(ws + ((size_t)96 << 20));
  short* q     = (short*)(ws + ((size_t)104 << 20));
  short* k     = (short*)(ws + ((size_t)112 << 20));
  short* v     = (short*)(ws + ((size_t)116 << 20));
  short* ao    = (short*)(ws + ((size_t)120 << 20));
  float* hid   = (float*)(ws + ((size_t)104 << 20));
  short* h2    = (short*)(ws + ((size_t)120 << 20));
  short* gu    = (short*)(ws + ((size_t)128 << 20));
  short* wdn_b = (short*)(ws + ((size_t)64 << 20));

  const dim3 b256(256);
  const dim3 b512(512);

  // weight pre-convert (fp32 -> bf16)
  cvt_f2b<<<dim3(16384), b256, 0, stream>>>(wgu, wgu_b);  // 32M elems
  cvt_f2b<<<dim3(2048),  b256, 0, stream>>>(wq,  wq_b);   // 4M
  cvt_f2b<<<dim3(1024),  b256, 0, stream>>>(wk,  wk_b);   // 2M
  cvt_f2b<<<dim3(1024),  b256, 0, stream>>>(wvp, wv_b);   // 2M
  cvt_f2b<<<dim3(2048),  b256, 0, stream>>>(wo,  wo_b);   // 4M

  transpose_f2b<<<dim3(32,32), b256, 0, stream>>>(hc, xT, HIDN, TSEQ);
  rmsnorm_b<<<dim3(TSEQ), b256, 0, stream>>>(xT, iln, h);

  gemm_bt<0,false><<<dim3(16,16), b256, 0, stream>>>(h, HIDN, wq_b, nullptr, q, 2048, 2048);
  gemm_bt<0,false><<<dim3(16,8),  b256, 0, stream>>>(h, HIDN, wk_b, nullptr, k, 1024, 2048);
  gemm_bt<0,false><<<dim3(16,8),  b256, 0, stream>>>(h, HIDN, wv_b, nullptr, v, 1024, 2048);

  qk_rms_rope<<<dim3(TSEQ*(NHQ+NHKV)), dim3(64), 0, stream>>>(q, k, cosb, sinb, qnw, knw);

  flash_attn<<<dim3(TSEQ/64, NHQ), b256, 0, stream>>>(q, k, v, ao);

  gemm_bt<1,false><<<dim3(16,16), b256, 0, stream>>>(ao, 2048, wo_b, xT, hid, 2048, 2048);

  // w_down fp32 -> bf16 into the now-dead wq_b..xT region (16M elems)
  cvt_f2b<<<dim3(8192), b256, 0, stream>>>(wdn, wdn_b);

  rmsnorm_f<<<dim3(TSEQ), b256, 0, stream>>>(hid, pln, h2);

  // gate_up: (2048 x 16384 x 2048) on the 8-phase 256x256 kernel
  gemm256<0><<<dim3(8,64), b512, 0, stream>>>(h2, HIDN, wgu_b, HIDN, gu, 16384, 2048);
  silu_mul<<<dim3((TSEQ*IMID/8)/256), b256, 0, stream>>>(gu);
  // down: (2048 x 2048 x 8192), split-K x4, atomicAdd into residual-loaded hid
  gemm256<3><<<dim3(8,8,4), b512, 0, stream>>>(gu, 2*IMID, wdn_b, IMID, hid, 2048, 2048);

  transpose_f2f<<<dim3(32,32), b256, 0, stream>>>(hid, (float*)d_out, TSEQ, HIDN);
}

// Round 3
// 879.113 us; speedup vs baseline: 1.2243x; 1.0472x over previous
//
#include <hip/hip_runtime.h>
#include <hip/hip_bf16.h>
#include <stdint.h>

#define NHQ   16
#define NHKV  8
#define DH    128
#define TSEQ  2048
#define HIDN  2048
#define IMID  8192
#define EPS   1e-6f
#define SCL   0.08838834764831845f  // 1/sqrt(128)

typedef __attribute__((ext_vector_type(8))) short short8;
typedef __attribute__((ext_vector_type(4))) short short4v;
typedef __attribute__((ext_vector_type(4))) float f32x4;
typedef unsigned int u32;
typedef unsigned short u16;

__device__ __forceinline__ float b2f(short s) {
  union { u32 u; float f; } cv; cv.u = ((u32)(u16)s) << 16; return cv.f;
}
__device__ __forceinline__ short f2b(float f) {
  union { float f; u32 u; } cv; cv.f = f;
  u32 u = cv.u;
  u32 r = u + 0x7FFFu + ((u >> 16) & 1u);
  return (short)(r >> 16);
}

// async 16B global -> LDS (dest = wave-uniform base + lane*16)  [m97-verified]
__device__ __forceinline__ void gll16(const void* g, void* l) {
  __builtin_amdgcn_global_load_lds(
      (const __attribute__((address_space(1))) u32*)g,
      (__attribute__((address_space(3))) u32*)l, 16, 0, 0);
}

// ---------------------------------------------------------------------------
// fp32 -> bf16 weight convert, 8 elems/thread
// ---------------------------------------------------------------------------
__global__ __launch_bounds__(256)
void cvt_f2b(const float* __restrict__ in, short* __restrict__ out)
{
  const size_t i = ((size_t)blockIdx.x*256 + threadIdx.x)*8;
  f32x4 a0 = *(const f32x4*)(in + i);
  f32x4 a1 = *(const f32x4*)(in + i + 4);
  short8 y;
  #pragma unroll
  for (int j = 0; j < 4; ++j) { y[j] = f2b(a0[j]); y[j+4] = f2b(a1[j]); }
  *(short8*)(out + i) = y;
}

// ---------------------------------------------------------------------------
// C = A @ B^T.  A: bf16 (M,K) lda.  B: bf16 (N,K) if !BF32 else fp32 (N,K),
// converted during staging.  fp32 accum.  128x128 tile, BK=64, 256 thr.
// (kept for the small QKV / wo GEMMs -- verified structure)
// ---------------------------------------------------------------------------
template<int EPI, bool BF32>
__global__ __launch_bounds__(256)
void gemm_bt(const short* __restrict__ A, int lda,
             const void* __restrict__ Bp,
             const void* __restrict__ RES,
             void* __restrict__ C, int N, int K)
{
  __shared__ __attribute__((aligned(16))) short As[128*64];
  __shared__ __attribute__((aligned(16))) short Bs[128*64];

  const int tid = threadIdx.x;
  const int wv = tid >> 6, ln = tid & 63;
  const int wm = wv >> 1, wn = wv & 1;
  const int l15 = ln & 15, quad = ln >> 4;
  const int bm0 = blockIdx.x * 128, bn0 = blockIdx.y * 128;

  f32x4 acc[4][4];
  #pragma unroll
  for (int i = 0; i < 4; ++i)
    #pragma unroll
    for (int j = 0; j < 4; ++j) acc[i][j] = (f32x4){0.f,0.f,0.f,0.f};

  const int srow = wv*32 + (ln >> 3);  // staging row base (+= i*8)
  const int schk = ln & 7;             // physical chunk this lane fills
  const int brow = tid >> 4;           // fp32-B staging coords
  const int bgrp = tid & 15;

  for (int kt = 0; kt < K; kt += 64) {
    #pragma unroll
    for (int i = 0; i < 4; ++i) {
      const int r = srow + i*8;
      const int g = schk ^ (r & 7);
      gll16(A + (size_t)(bm0 + r)*lda + kt + g*8,
            (char*)As + (wv*32 + i*8)*128);
      if (!BF32)
        gll16((const short*)Bp + (size_t)(bn0 + r)*K + kt + g*8,
              (char*)Bs + (wv*32 + i*8)*128);
    }
    if (BF32) {
      #pragma unroll
      for (int p = 0; p < 8; ++p) {
        const int r = p*16 + brow;
        f32x4 w4 = *(const f32x4*)((const float*)Bp + (size_t)(bn0 + r)*K + kt + bgrp*4);
        short4v s4;
        #pragma unroll
        for (int j = 0; j < 4; ++j) s4[j] = f2b(w4[j]);
        *(short4v*)(Bs + r*64 + (((bgrp >> 1) ^ (r & 7))*8) + (bgrp & 1)*4) = s4;
      }
    }
    __syncthreads();

    #pragma unroll
    for (int ks = 0; ks < 2; ++ks) {
      short8 af[4], bfr[4];
      #pragma unroll
      for (int mi = 0; mi < 4; ++mi) {
        const int r = wm*64 + mi*16 + l15;
        const int p = (quad + ks*4) ^ (r & 7);
        af[mi] = *(const short8*)(As + r*64 + p*8);
      }
      #pragma unroll
      for (int ni = 0; ni < 4; ++ni) {
        const int r = wn*64 + ni*16 + l15;
        const int p = (quad + ks*4) ^ (r & 7);
        bfr[ni] = *(const short8*)(Bs + r*64 + p*8);
      }
      #pragma unroll
      for (int mi = 0; mi < 4; ++mi)
        #pragma unroll
        for (int ni = 0; ni < 4; ++ni)
          acc[mi][ni] = __builtin_amdgcn_mfma_f32_16x16x32_bf16(
              af[mi], bfr[ni], acc[mi][ni], 0, 0, 0);
    }
    __syncthreads();
  }

  #pragma unroll
  for (int mi = 0; mi < 4; ++mi) {
    #pragma unroll
    for (int reg = 0; reg < 4; ++reg) {
      const int row = bm0 + wm*64 + mi*16 + quad*4 + reg;
      #pragma unroll
      for (int ni = 0; ni < 4; ++ni) {
        const int col = bn0 + wn*64 + ni*16 + l15;
        const size_t off = (size_t)row*N + col;
        const float v = acc[mi][ni][reg];
        if (EPI == 0)      ((short*)C)[off] = f2b(v);
        else if (EPI == 1) ((float*)C)[off] = b2f(((const short*)RES)[off]) + v;
        else               ((float*)C)[off] = ((const float*)RES)[off] + v;
      }
    }
  }
}

// ---------------------------------------------------------------------------
// 256x256 8-phase pipelined GEMM (T1+T2+T3+T4+T5).  C = A @ B^T, bf16 in,
// fp32 accum.  A: (M,K) lda.  B: (N,K) ldb.  512 thr = 8 waves (2M x 4N),
// per-wave output 128x64.  BK=64; 2 K-tiles double-buffered in 128 KiB LDS,
// each tile split into 2 halves (A0,A1,B0,B1 regions of 16 KiB).
// Per phase: ds_read one quadrant's frags | stage ONE half-tile (2x gll16)
// | s_barrier | lgkmcnt(0) | setprio(1) 16x MFMA setprio(0) | s_barrier.
// Counted s_waitcnt vmcnt(4) ONLY at phases 4 and 8 -- prefetch loads stay
// in flight across barriers (no vmcnt(0) drain anywhere in the main loop).
// Stage schedule (iter computes tiles u=2i [slot0, ph1-4], u+1 [slot1, ph5-8]):
//   ph1: A0->s1(u+1)  ph2: A1->s1(u+1)  ph3: B0->s0(u+2)  ph4: B1->s0(u+2)
//   ph5: A0->s0(u+2)  ph6: A1->s0(u+2)  ph7: B0->s1(u+3)  ph8: B1->s1(u+3)
// Every staged region's last reads finish >=1 barrier before the stage issues,
// and every region's first re-read is gated behind a vmcnt(4) that retires it
// (invariant: each VMC4 retires all but the 2 newest STG-pairs; every
// stage->first-reread distance is >=2 STG-pairs with a VMC4 between).
// sched_barrier(0) after every s_barrier: s_barrier is IntrNoMem in LLVM, so
// without the pin the scheduler may hoist post-barrier ds_reads above it
// (m152 race class).  LDS chunk-XOR swizzle (phys 16B chunk p of row r holds
// logical p^(r&7)): conflict-free ds_read_b128 via pre-swizzled global src.
// EPI: 0 = bf16 store; 3 = fp32 atomicAdd (split-K over blockIdx.z).
// Requires: M%256==0, N%256==0, Ko%128==0 (NT even).
// ---------------------------------------------------------------------------
#define BAR256()   do { __builtin_amdgcn_s_barrier();                      \
                        __builtin_amdgcn_sched_barrier(0); } while (0)
#define LGKM0()    do { asm volatile("s_waitcnt lgkmcnt(0)" ::: "memory"); \
                        __builtin_amdgcn_sched_barrier(0); } while (0)
#define VMC4()     do { asm volatile("s_waitcnt vmcnt(4)" ::: "memory");   \
                        __builtin_amdgcn_sched_barrier(0); } while (0)

template<int EPI>
__global__ __launch_bounds__(512, 2)
void gemm256(const short* __restrict__ A, int lda,
             const short* __restrict__ B, int ldb,
             void* __restrict__ C, int N, int Ko)
{
  __shared__ __attribute__((aligned(16))) char L[131072];
  // A slot s half h: (s*2+h)*16384   B: +65536

  const int tid = threadIdx.x;
  const int wv = tid >> 6, ln = tid & 63;
  const int wm = wv >> 2, wn = wv & 3;
  const int l15 = ln & 15, quad = ln >> 4;

  // XCD-aware bijective swizzle (nwg % 8 == 0 for all our grids)
  int bx, by;
  {
    const int nwg  = gridDim.x * gridDim.y;
    const int orig = blockIdx.y * gridDim.x + blockIdx.x;
    const int wg   = (orig & 7) * (nwg >> 3) + (orig >> 3);
    bx = wg % gridDim.x;
    by = wg / gridDim.x;
  }
  const int bm0 = bx * 256, bn0 = by * 256;
  const int k0  = blockIdx.z * Ko;

  // staging constants: thread fills row (i*64 + wv*8 + (ln>>3)), phys chunk ln&7;
  // logical chunk g = (ln&7) ^ (row&7), and row&7 == (ln>>3)&7 for all i.
  const int srow = wv*8 + (ln >> 3);
  const int g8   = ((ln & 7) ^ ((ln >> 3) & 7)) * 8;
  const short* Ab = A + (size_t)bm0 * lda + k0 + g8;
  const short* Bb = B + (size_t)bn0 * ldb + k0 + g8;

  // LDS-read constants (phys chunk = (ks*4+quad) ^ (row&7), row&7 == l15&7)
  const int aro = l15 * 128;
  const int p0  = ((quad    ) ^ (l15 & 7)) * 16;
  const int p1  = ((quad + 4) ^ (l15 & 7)) * 16;

  f32x4 acc[8][4];
  #pragma unroll
  for (int i = 0; i < 8; ++i)
    #pragma unroll
    for (int j = 0; j < 4; ++j) acc[i][j] = (f32x4){0.f,0.f,0.f,0.f};

  short8 af[4][2], bf0[2][2], bf1[2][2];

  const int NT = Ko >> 6;   // K-tiles (even)
  const int NI = NT >> 1;

#define STG(base, ld, s, h, t, isB)                                          \
  { char* r_ = L + (isB)*65536 + ((s)*2 + (h))*16384 + wv*1024;              \
    _Pragma("unroll")                                                        \
    for (int i_ = 0; i_ < 2; ++i_)                                           \
      gll16(base + (size_t)((h)*128 + i_*64 + srow)*(ld) + (size_t)(t)*64,   \
            r_ + i_*8192); }

#define LD_A(s, mh)                                                          \
  { const char* a_ = L + ((s)*2 + wm)*16384 + (mh)*8192 + aro;               \
    _Pragma("unroll")                                                        \
    for (int m_ = 0; m_ < 4; ++m_) {                                         \
      af[m_][0] = *(const short8*)(a_ + m_*2048 + p0);                       \
      af[m_][1] = *(const short8*)(a_ + m_*2048 + p1);                       \
    } }

#define LD_B(s, nh, bfv)                                                     \
  { const char* b_ = L + 65536 + ((s)*2 + (wn>>1))*16384 + (wn&1)*8192       \
                     + (nh)*4096 + aro;                                      \
    _Pragma("unroll")                                                        \
    for (int n_ = 0; n_ < 2; ++n_) {                                         \
      bfv[n_][0] = *(const short8*)(b_ + n_*2048 + p0);                      \
      bfv[n_][1] = *(const short8*)(b_ + n_*2048 + p1);                      \
    } }

#define MM_Q(mh, nh, bfv)                                                    \
  { __builtin_amdgcn_s_setprio(1);                                           \
    _Pragma("unroll")                                                        \
    for (int m_ = 0; m_ < 4; ++m_)                                           \
      _Pragma("unroll")                                                      \
      for (int n_ = 0; n_ < 2; ++n_) {                                       \
        acc[(mh)*4+m_][(nh)*2+n_] = __builtin_amdgcn_mfma_f32_16x16x32_bf16( \
            af[m_][0], bfv[n_][0], acc[(mh)*4+m_][(nh)*2+n_], 0, 0, 0);      \
        acc[(mh)*4+m_][(nh)*2+n_] = __builtin_amdgcn_mfma_f32_16x16x32_bf16( \
            af[m_][1], bfv[n_][1], acc[(mh)*4+m_][(nh)*2+n_], 0, 0, 0);      \
      }                                                                      \
    __builtin_amdgcn_s_setprio(0); }

  // prologue: tile0 -> slot0 (all 4 halves); tile1 B halves -> slot1.
  // 12 loads/wave issued; vmcnt(4) retires the 8 of tile0, leaves tile1-B (4).
  STG(Ab, lda, 0,0, 0, 0); STG(Ab, lda, 0,1, 0, 0);
  STG(Bb, ldb, 0,0, 0, 1); STG(Bb, ldb, 0,1, 0, 1);
  STG(Bb, ldb, 1,0, 1, 1); STG(Bb, ldb, 1,1, 1, 1);
  VMC4();
  BAR256();

  for (int it = 0; it < NI; ++it) {
    const int u   = it*2;
    const int tA1 = u + 1;
    const int t2  = (u+2 < NT) ? u+2 : NT-1;   // clamped: keeps vmcnt counting
    const int t3  = (u+3 < NT) ? u+3 : NT-1;   // exact; garbage data never read

    // ph1: Q(m0,n0) slot0 | stage A0->s1 (u+1)
    LD_A(0,0); LD_B(0,0,bf0);
    STG(Ab, lda, 1,0, tA1, 0);
    BAR256(); LGKM0();
    MM_Q(0,0,bf0);
    BAR256();
    // ph2: Q(m0,n1) slot0 | stage A1->s1 (u+1)
    LD_B(0,1,bf1);
    STG(Ab, lda, 1,1, tA1, 0);
    BAR256(); LGKM0();
    MM_Q(0,1,bf1);
    BAR256();
    // ph3: Q(m1,n0) slot0 | stage B0->s0 (u+2)
    LD_A(0,1);
    STG(Bb, ldb, 0,0, t2, 1);
    BAR256(); LGKM0();
    MM_Q(1,0,bf0);
    BAR256();
    // ph4: Q(m1,n1) slot0 | stage B1->s0 (u+2) | vmcnt(4)
    STG(Bb, ldb, 0,1, t2, 1);
    BAR256(); LGKM0();
    MM_Q(1,1,bf1);
    VMC4();
    BAR256();
    // ph5: Q(m0,n0) slot1 | stage A0->s0 (u+2)
    LD_A(1,0); LD_B(1,0,bf0);
    STG(Ab, lda, 0,0, t2, 0);
    BAR256(); LGKM0();
    MM_Q(0,0,bf0);
    BAR256();
    // ph6: Q(m0,n1) slot1 | stage A1->s0 (u+2)
    LD_B(1,1,bf1);
    STG(Ab, lda, 0,1, t2, 0);
    BAR256(); LGKM0();
    MM_Q(0,1,bf1);
    BAR256();
    // ph7: Q(m1,n0) slot1 | stage B0->s1 (u+3)
    LD_A(1,1);
    STG(Bb, ldb, 1,0, t3, 1);
    BAR256(); LGKM0();
    MM_Q(1,0,bf0);
    BAR256();
    // ph8: Q(m1,n1) slot1 | stage B1->s1 (u+3) | vmcnt(4)
    STG(Bb, ldb, 1,1, t3, 1);
    BAR256(); LGKM0();
    MM_Q(1,1,bf1);
    VMC4();
    BAR256();
  }

  #pragma unroll
  for (int mi = 0; mi < 8; ++mi) {
    #pragma unroll
    for (int reg = 0; reg < 4; ++reg) {
      const int row = bm0 + wm*128 + mi*16 + quad*4 + reg;
      #pragma unroll
      for (int ni = 0; ni < 4; ++ni) {
        const int col = bn0 + wn*64 + ni*16 + l15;
        const size_t off = (size_t)row*N + col;
        const float v = acc[mi][ni][reg];
        if (EPI == 0) ((short*)C)[off] = f2b(v);
        else          atomicAdd((float*)C + off, v);
      }
    }
  }
#undef STG
#undef LD_A
#undef LD_B
#undef MM_Q
}

// ---------------------------------------------------------------------------
// fp32 (rows_in, cols_in) -> bf16 (cols_in, rows_in)
// ---------------------------------------------------------------------------
__global__ __launch_bounds__(256)
void transpose_f2b(const float* __restrict__ in, short* __restrict__ out,
                   int rows_in, int cols_in)
{
  __shared__ float tile[64][65];
  const int c0 = blockIdx.x*64, r0 = blockIdx.y*64;
  const int tx = threadIdx.x & 63, ty = threadIdx.x >> 6;
  #pragma unroll
  for (int i = 0; i < 16; ++i) {
    const int r = ty + i*4;
    tile[r][tx] = in[(size_t)(r0+r)*cols_in + c0 + tx];
  }
  __syncthreads();
  #pragma unroll
  for (int i = 0; i < 16; ++i) {
    const int r = ty + i*4;
    out[(size_t)(c0+r)*rows_in + r0 + tx] = f2b(tile[tx][r]);
  }
}

// fp32 (rows_in, cols_in) -> fp32 (cols_in, rows_in)
__global__ __launch_bounds__(256)
void transpose_f2f(const float* __restrict__ in, float* __restrict__ out,
                   int rows_in, int cols_in)
{
  __shared__ float tile[64][65];
  const int c0 = blockIdx.x*64, r0 = blockIdx.y*64;
  const int tx = threadIdx.x & 63, ty = threadIdx.x >> 6;
  #pragma unroll
  for (int i = 0; i < 16; ++i) {
    const int r = ty + i*4;
    tile[r][tx] = in[(size_t)(r0+r)*cols_in + c0 + tx];
  }
  __syncthreads();
  #pragma unroll
  for (int i = 0; i < 16; ++i) {
    const int r = ty + i*4;
    out[(size_t)(c0+r)*rows_in + r0 + tx] = tile[tx][r];
  }
}

// ---------------------------------------------------------------------------
// row RMSNorm over HID=2048. X bf16, W fp32, Y bf16.
// ---------------------------------------------------------------------------
__global__ __launch_bounds__(256)
void rmsnorm_b(const short* __restrict__ X, const float* __restrict__ W,
               short* __restrict__ Y)
{
  const int row = blockIdx.x, tid = threadIdx.x;
  const int wv = tid >> 6, ln = tid & 63;
  const size_t base = (size_t)row*HIDN + tid*8;
  short8 xv = *(const short8*)(X + base);
  float x[8];
  #pragma unroll
  for (int j = 0; j < 8; ++j) x[j] = b2f(xv[j]);
  float s = 0.f;
  #pragma unroll
  for (int j = 0; j < 8; ++j) s += x[j]*x[j];
  #pragma unroll
  for (int off = 32; off; off >>= 1) s += __shfl_xor(s, off, 64);
  __shared__ float red[4];
  if (ln == 0) red[wv] = s;
  __syncthreads();
  const float tot = red[0]+red[1]+red[2]+red[3];
  const float r = rsqrtf(tot*(1.0f/HIDN) + EPS);
  f32x4 w0 = *(const f32x4*)(W + tid*8);
  f32x4 w1 = *(const f32x4*)(W + tid*8 + 4);
  short8 y;
  #pragma unroll
  for (int j = 0; j < 4; ++j) y[j]   = f2b(x[j]*r*w0[j]);
  #pragma unroll
  for (int j = 0; j < 4; ++j) y[j+4] = f2b(x[j+4]*r*w1[j]);
  *(short8*)(Y + base) = y;
}

// X fp32, W fp32, Y bf16
__global__ __launch_bounds__(256)
void rmsnorm_f(const float* __restrict__ X, const float* __restrict__ W,
               short* __restrict__ Y)
{
  const int row = blockIdx.x, tid = threadIdx.x;
  const int wv = tid >> 6, ln = tid & 63;
  const size_t base = (size_t)row*HIDN + tid*8;
  f32x4 a0 = *(const f32x4*)(X + base);
  f32x4 a1 = *(const f32x4*)(X + base + 4);
  float x[8] = {a0[0],a0[1],a0[2],a0[3],a1[0],a1[1],a1[2],a1[3]};
  float s = 0.f;
  #pragma unroll
  for (int j = 0; j < 8; ++j) s += x[j]*x[j];
  #pragma unroll
  for (int off = 32; off; off >>= 1) s += __shfl_xor(s, off, 64);
  __shared__ float red[4];
  if (ln == 0) red[wv] = s;
  __syncthreads();
  const float tot = red[0]+red[1]+red[2]+red[3];
  const float r = rsqrtf(tot*(1.0f/HIDN) + EPS);
  f32x4 w0 = *(const f32x4*)(W + tid*8);
  f32x4 w1 = *(const f32x4*)(W + tid*8 + 4);
  short8 y;
  #pragma unroll
  for (int j = 0; j < 4; ++j) y[j]   = f2b(x[j]*r*w0[j]);
  #pragma unroll
  for (int j = 0; j < 4; ++j) y[j+4] = f2b(x[j+4]*r*w1[j]);
  *(short8*)(Y + base) = y;
}

// ---------------------------------------------------------------------------
// fused per-head RMSNorm (D=128) + RoPE, in-place on bf16 q/k.
// ---------------------------------------------------------------------------
__global__ __launch_bounds__(64)
void qk_rms_rope(short* __restrict__ Qb, short* __restrict__ Kb,
                 const float* __restrict__ cosb, const float* __restrict__ sinb,
                 const float* __restrict__ qw, const float* __restrict__ kw)
{
  const int b = blockIdx.x;
  const int hi = b % (NHQ + NHKV);
  const int t  = b / (NHQ + NHKV);
  const int ln = threadIdx.x;
  short* row; const float* w;
  if (hi < NHQ) { row = Qb + (size_t)t*(NHQ*DH) + hi*DH; w = qw; }
  else          { row = Kb + (size_t)t*(NHKV*DH) + (hi-NHQ)*DH; w = kw; }
  float x0 = b2f(row[ln]), x1 = b2f(row[ln+64]);
  float s = x0*x0 + x1*x1;
  #pragma unroll
  for (int off = 32; off; off >>= 1) s += __shfl_xor(s, off, 64);
  const float r = rsqrtf(s*(1.0f/DH) + EPS);
  const float n0 = x0*r*w[ln];
  const float n1 = x1*r*w[ln+64];
  const float* cr = cosb + (size_t)t*DH;
  const float* sr = sinb + (size_t)t*DH;
  const float c0 = cr[ln], c1 = cr[ln+64];
  const float s0 = sr[ln], s1 = sr[ln+64];
  row[ln]    = f2b(n0*c0 - n1*s0);
  row[ln+64] = f2b(n1*c1 + n0*s1);
}

// ---------------------------------------------------------------------------
// causal flash attention, 16x16x32 MFMA.
// This round: XOR chunk-swizzle on ALL THREE LDS buffers (G4: row strides
// are multiples of 128B -> bank = f(chunk) only -> 8-16x serialization;
// measured 3.1e7 SQ_LDS_BANK_CONFLICT = ~30% of kernel time).
//   Ks: phys 16B chunk p of row r holds logical p^(r&7) -- staged via
//       pre-swizzled GLOBAL source into linear gll16 dest (rule #21).
//   Vt: register-transpose write at phys chunk (logical^(d&7)); PV read
//       at gp^(l15&7).  Ps: same pattern per 64-short row.
// All access patterns verified to 8 accesses/bank = HW minimum.
// Plus causal load-balance: bx interleave remap (work = bx+1 tiles).
// ---------------------------------------------------------------------------
__global__ __launch_bounds__(256)
void flash_attn(const short* __restrict__ Q, const short* __restrict__ Kb,
                const short* __restrict__ Vb, short* __restrict__ O)
{
  __shared__ __attribute__((aligned(16))) short Ks[64*128];  // [s][d] swz
  __shared__ __attribute__((aligned(16))) short Vt[128*64];  // [d][s] swz
  __shared__ __attribute__((aligned(16))) short Ps[4*16*64]; // per-wave swz

  const int tid = threadIdx.x, wv = tid >> 6, ln = tid & 63;
  const int l15 = ln & 15, quad = ln >> 4;
  const int hh = blockIdx.y, kvh = hh >> 1;
  // interleave remap: pair long & short causal blocks in dispatch order
  const int nbx = gridDim.x;
  const int bxr = blockIdx.x;
  const int bx  = (bxr & 1) ? (nbx - 1 - (bxr >> 1)) : (bxr >> 1);
  const int m0 = bx * 64;
  const int qm0 = m0 + wv*16;

  short8 qf[4];
  {
    const short* qb = Q + (size_t)(qm0 + l15)*(NHQ*DH) + hh*DH + quad*8;
    #pragma unroll
    for (int ks = 0; ks < 4; ++ks) qf[ks] = *(const short8*)(qb + ks*32);
  }

  f32x4 oa[8];
  #pragma unroll
  for (int i = 0; i < 8; ++i) oa[i] = (f32x4){0.f,0.f,0.f,0.f};
  float m_r[4] = {-1e30f,-1e30f,-1e30f,-1e30f};
  float l_r[4] = {0.f,0.f,0.f,0.f};

  const int l7 = l15 & 7;

  const int ntile = bx + 1;
  for (int st = 0; st < ntile; ++st) {
    const int s0 = st*64;
    __syncthreads();

    // K stage: lane (quad,l15) fills row r, phys chunk l15; source chunk
    // pre-swizzled so phys p holds logical p^(r&7).  r&7 = 4*(it&1)+quad.
    #pragma unroll
    for (int it = 0; it < 4; ++it) {
      const int r = (wv*4 + it)*4 + quad;
      const int g = l15 ^ (4*(it & 1) + quad);
      gll16(Kb + (size_t)(s0 + r)*(NHKV*DH) + kvh*DH + g*8,
            (char*)Ks + (wv*4 + it)*1024);
    }
    // V transpose-stage: logical chunk (sh*4+cb) of row d at phys ^(d&7)
    {
      const int d = tid & 127, sh = tid >> 7;
      #pragma unroll
      for (int cb = 0; cb < 4; ++cb) {
        short8 t8;
        #pragma unroll
        for (int j = 0; j < 8; ++j)
          t8[j] = Vb[(size_t)(s0 + sh*32 + cb*8 + j)*(NHKV*DH) + kvh*DH + d];
        *(short8*)(Vt + d*64 + (((sh*4 + cb) ^ (d & 7))*8)) = t8;
      }
    }
    __syncthreads();

    f32x4 sc[4];
    #pragma unroll
    for (int ci = 0; ci < 4; ++ci) {
      f32x4 a = (f32x4){0.f,0.f,0.f,0.f};
      #pragma unroll
      for (int ks = 0; ks < 4; ++ks) {
        const int r = ci*16 + l15;
        const int p = (quad + ks*4) ^ l7;     // logical quad+ks*4, r&7==l7
        short8 kf = *(const short8*)(Ks + r*128 + p*8);
        a = __builtin_amdgcn_mfma_f32_16x16x32_bf16(qf[ks], kf, a, 0, 0, 0);
      }
      sc[ci] = a;
    }

    float alpha[4];
    #pragma unroll
    for (int reg = 0; reg < 4; ++reg) {
      const int grow = qm0 + quad*4 + reg;
      float rmax = -1e30f;
      #pragma unroll
      for (int ci = 0; ci < 4; ++ci) {
        float v = sc[ci][reg]*SCL;
        const int gs = s0 + ci*16 + l15;
        v = (gs <= grow) ? v : -1e30f;
        sc[ci][reg] = v;
        rmax = fmaxf(rmax, v);
      }
      #pragma unroll
      for (int off = 1; off < 16; off <<= 1)
        rmax = fmaxf(rmax, __shfl_xor(rmax, off, 64));
      const float mn = fmaxf(m_r[reg], rmax);
      alpha[reg] = __expf(m_r[reg] - mn);
      m_r[reg] = mn;
      float rsum = 0.f;
      #pragma unroll
      for (int ci = 0; ci < 4; ++ci) {
        const float p = __expf(sc[ci][reg] - mn);
        sc[ci][reg] = p;
        rsum += p;
      }
      #pragma unroll
      for (int off = 1; off < 16; off <<= 1)
        rsum += __shfl_xor(rsum, off, 64);
      l_r[reg] = l_r[reg]*alpha[reg] + rsum;
    }
    #pragma unroll
    for (int ni = 0; ni < 8; ++ni)
      #pragma unroll
      for (int reg = 0; reg < 4; ++reg) oa[ni][reg] *= alpha[reg];

    // Ps write: row=quad*4+reg, col=ci*16+l15 -> chunk (ci*2+(l15>>3))^(row&7)
    #pragma unroll
    for (int ci = 0; ci < 4; ++ci)
      #pragma unroll
      for (int reg = 0; reg < 4; ++reg) {
        const int row = quad*4 + reg;
        const int pc  = (ci*2 + (l15 >> 3)) ^ (row & 7);
        Ps[wv*1024 + row*64 + pc*8 + l7] = f2b(sc[ci][reg]);
      }

    __syncthreads();

    #pragma unroll
    for (int ks = 0; ks < 2; ++ks) {
      const int gp = quad + ks*4;
      const int pp = gp ^ l7;                  // Ps row l15: phys chunk
      short8 pf = *(const short8*)(Ps + wv*1024 + l15*64 + pp*8);
      #pragma unroll
      for (int ni = 0; ni < 8; ++ni) {
        const int d = ni*16 + l15;
        short8 vf = *(const short8*)(Vt + d*64 + ((gp ^ l7)*8));
        oa[ni] = __builtin_amdgcn_mfma_f32_16x16x32_bf16(pf, vf, oa[ni], 0, 0, 0);
      }
    }
  }

  #pragma unroll
  for (int reg = 0; reg < 4; ++reg) {
    const float inv = 1.0f / l_r[reg];
    const int row = qm0 + quad*4 + reg;
    #pragma unroll
    for (int ni = 0; ni < 8; ++ni)
      O[(size_t)row*(NHQ*DH) + hh*DH + ni*16 + l15] = f2b(oa[ni][reg]*inv);
  }
}

// ---------------------------------------------------------------------------
// gate half of gu (T, 2I)  <-  silu(gate) * up, in place (bf16)
// ---------------------------------------------------------------------------
__global__ __launch_bounds__(256)
void silu_mul(short* __restrict__ gu)
{
  const size_t idx = ((size_t)blockIdx.x*256 + threadIdx.x)*8;
  const size_t t = idx / IMID;
  const size_t i = idx % IMID;
  short* gp = gu + t*(2*IMID) + i;
  short8 g8 = *(const short8*)gp;
  short8 u8 = *(const short8*)(gp + IMID);
  short8 o;
  #pragma unroll
  for (int j = 0; j < 8; ++j) {
    const float g = b2f(g8[j]);
    const float u = b2f(u8[j]);
    const float sl = g / (1.f + __expf(-g));
    o[j] = f2b(sl*u);
  }
  *(short8*)gp = o;
}

// ---------------------------------------------------------------------------
extern "C" void kernel_launch(void* const* d_in, const int* in_sizes, int n_in,
                              void* d_out, int out_size, void* d_ws, size_t ws_size,
                              hipStream_t stream)
{
  const float* hc   = (const float*)d_in[0];
  const float* cosb = (const float*)d_in[1];
  const float* sinb = (const float*)d_in[2];
  const float* wq   = (const float*)d_in[5];
  const float* wk   = (const float*)d_in[6];
  const float* wvp  = (const float*)d_in[7];
  const float* wo   = (const float*)d_in[8];
  const float* wgu  = (const float*)d_in[9];
  const float* wdn  = (const float*)d_in[10];
  const float* iln  = (const float*)d_in[11];
  const float* pln  = (const float*)d_in[12];
  const float* qnw  = (const float*)d_in[13];
  const float* knw  = (const float*)d_in[14];

  // workspace map (192 MB peak):
  //  wgu_b 0-64 | wq_b 64-72 | wk_b 72-76 | wv_b 76-80 | wo_b 80-88
  //  xT 88-96 | h 96-104 | q 104-112 | k 112-116 | v 116-120 | ao 120-128
  //  hid (fp32) 104-120 (over q/k/v, dead after flash)
  //  h2 120-128 (over ao, dead after wo-gemm) | gu 128-192
  //  wdn_b 64-96 (over wq_b..xT, all dead after wo-gemm)
  char* ws = (char*)d_ws;
  short* wgu_b = (short*)(ws);
  short* wq_b  = (short*)(ws + ((size_t)64 << 20));
  short* wk_b  = (short*)(ws + ((size_t)72 << 20));
  short* wv_b  = (short*)(ws + ((size_t)76 << 20));
  short* wo_b  = (short*)(ws + ((size_t)80 << 20));
  short* xT    = (short*)(ws + ((size_t)88 << 20));
  short* h     = (short*)(ws + ((size_t)96 << 20));
  short* q     = (short*)(ws + ((size_t)104 << 20));
  short* k     = (short*)(ws + ((size_t)112 << 20));
  short* v     = (short*)(ws + ((size_t)116 << 20));
  short* ao    = (short*)(ws + ((size_t)120 << 20));
  float* hid   = (float*)(ws + ((size_t)104 << 20));
  short* h2    = (short*)(ws + ((size_t)120 << 20));
  short* gu    = (short*)(ws + ((size_t)128 << 20));
  short* wdn_b = (short*)(ws + ((size_t)64 << 20));

  const dim3 b256(256);
  const dim3 b512(512);

  // weight pre-convert (fp32 -> bf16)
  cvt_f2b<<<dim3(16384), b256, 0, stream>>>(wgu, wgu_b);  // 32M elems
  cvt_f2b<<<dim3(2048),  b256, 0, stream>>>(wq,  wq_b);   // 4M
  cvt_f2b<<<dim3(1024),  b256, 0, stream>>>(wk,  wk_b);   // 2M
  cvt_f2b<<<dim3(1024),  b256, 0, stream>>>(wvp, wv_b);   // 2M
  cvt_f2b<<<dim3(2048),  b256, 0, stream>>>(wo,  wo_b);   // 4M

  transpose_f2b<<<dim3(32,32), b256, 0, stream>>>(hc, xT, HIDN, TSEQ);
  rmsnorm_b<<<dim3(TSEQ), b256, 0, stream>>>(xT, iln, h);

  gemm_bt<0,false><<<dim3(16,16), b256, 0, stream>>>(h, HIDN, wq_b, nullptr, q, 2048, 2048);
  gemm_bt<0,false><<<dim3(16,8),  b256, 0, stream>>>(h, HIDN, wk_b, nullptr, k, 1024, 2048);
  gemm_bt<0,false><<<dim3(16,8),  b256, 0, stream>>>(h, HIDN, wv_b, nullptr, v, 1024, 2048);

  qk_rms_rope<<<dim3(TSEQ*(NHQ+NHKV)), dim3(64), 0, stream>>>(q, k, cosb, sinb, qnw, knw);

  flash_attn<<<dim3(TSEQ/64, NHQ), b256, 0, stream>>>(q, k, v, ao);

  gemm_bt<1,false><<<dim3(16,16), b256, 0, stream>>>(ao, 2048, wo_b, xT, hid, 2048, 2048);

  // w_down fp32 -> bf16 into the now-dead wq_b..xT region (16M elems)
  cvt_f2b<<<dim3(8192), b256, 0, stream>>>(wdn, wdn_b);

  rmsnorm_f<<<dim3(TSEQ), b256, 0, stream>>>(hid, pln, h2);

  // gate_up: (2048 x 16384 x 2048) on the 8-phase 256x256 kernel
  gemm256<0><<<dim3(8,64), b512, 0, stream>>>(h2, HIDN, wgu_b, HIDN, gu, 16384, 2048);
  silu_mul<<<dim3((TSEQ*IMID/8)/256), b256, 0, stream>>>(gu);
  // down: (2048 x 2048 x 8192), split-K x4, atomicAdd into residual-loaded hid
  gemm256<3><<<dim3(8,8,4), b512, 0, stream>>>(gu, 2*IMID, wdn_b, IMID, hid, 2048, 2048);

  transpose_f2f<<<dim3(32,32), b256, 0, stream>>>(hid, (float*)d_out, TSEQ, HIDN);
}

// Round 4
// 753.278 us; speedup vs baseline: 1.4288x; 1.1671x over previous
//
#include <hip/hip_runtime.h>
#include <hip/hip_bf16.h>
#include <stdint.h>

#define NHQ   16
#define NHKV  8
#define DH    128
#define TSEQ  2048
#define HIDN  2048
#define IMID  8192
#define EPS   1e-6f
#define SCL   0.08838834764831845f  // 1/sqrt(128)

typedef __attribute__((ext_vector_type(8))) short short8;
typedef __attribute__((ext_vector_type(4))) short short4v;
typedef __attribute__((ext_vector_type(4))) float f32x4;
typedef unsigned int u32;
typedef unsigned short u16;

__device__ __forceinline__ float b2f(short s) {
  union { u32 u; float f; } cv; cv.u = ((u32)(u16)s) << 16; return cv.f;
}
__device__ __forceinline__ short f2b(float f) {
  union { float f; u32 u; } cv; cv.f = f;
  u32 u = cv.u;
  u32 r = u + 0x7FFFu + ((u >> 16) & 1u);
  return (short)(r >> 16);
}

// async 16B global -> LDS (dest = wave-uniform base + lane*16)  [m97-verified]
__device__ __forceinline__ void gll16(const void* g, void* l) {
  __builtin_amdgcn_global_load_lds(
      (const __attribute__((address_space(1))) u32*)g,
      (__attribute__((address_space(3))) u32*)l, 16, 0, 0);
}

// ---------------------------------------------------------------------------
// fp32 -> bf16 weight convert, 8 elems/thread
// ---------------------------------------------------------------------------
__global__ __launch_bounds__(256)
void cvt_f2b(const float* __restrict__ in, short* __restrict__ out)
{
  const size_t i = ((size_t)blockIdx.x*256 + threadIdx.x)*8;
  f32x4 a0 = *(const f32x4*)(in + i);
  f32x4 a1 = *(const f32x4*)(in + i + 4);
  short8 y;
  #pragma unroll
  for (int j = 0; j < 4; ++j) { y[j] = f2b(a0[j]); y[j+4] = f2b(a1[j]); }
  *(short8*)(out + i) = y;
}

// ---------------------------------------------------------------------------
// C = A @ B^T.  A: bf16 (M,K) lda.  B: bf16 (N,K).  fp32 accum.
// 128x128 tile, BK=64, 256 thr.  (kept for the wo GEMM)
// EPI: 0 = bf16 store; 1 = fp32 store + bf16 residual
// ---------------------------------------------------------------------------
template<int EPI, bool BF32>
__global__ __launch_bounds__(256)
void gemm_bt(const short* __restrict__ A, int lda,
             const void* __restrict__ Bp,
             const void* __restrict__ RES,
             void* __restrict__ C, int N, int K)
{
  __shared__ __attribute__((aligned(16))) short As[128*64];
  __shared__ __attribute__((aligned(16))) short Bs[128*64];

  const int tid = threadIdx.x;
  const int wv = tid >> 6, ln = tid & 63;
  const int wm = wv >> 1, wn = wv & 1;
  const int l15 = ln & 15, quad = ln >> 4;
  const int bm0 = blockIdx.x * 128, bn0 = blockIdx.y * 128;

  f32x4 acc[4][4];
  #pragma unroll
  for (int i = 0; i < 4; ++i)
    #pragma unroll
    for (int j = 0; j < 4; ++j) acc[i][j] = (f32x4){0.f,0.f,0.f,0.f};

  const int srow = wv*32 + (ln >> 3);  // staging row base (+= i*8)
  const int schk = ln & 7;             // physical chunk this lane fills
  const int brow = tid >> 4;           // fp32-B staging coords
  const int bgrp = tid & 15;

  for (int kt = 0; kt < K; kt += 64) {
    #pragma unroll
    for (int i = 0; i < 4; ++i) {
      const int r = srow + i*8;
      const int g = schk ^ (r & 7);
      gll16(A + (size_t)(bm0 + r)*lda + kt + g*8,
            (char*)As + (wv*32 + i*8)*128);
      if (!BF32)
        gll16((const short*)Bp + (size_t)(bn0 + r)*K + kt + g*8,
              (char*)Bs + (wv*32 + i*8)*128);
    }
    if (BF32) {
      #pragma unroll
      for (int p = 0; p < 8; ++p) {
        const int r = p*16 + brow;
        f32x4 w4 = *(const f32x4*)((const float*)Bp + (size_t)(bn0 + r)*K + kt + bgrp*4);
        short4v s4;
        #pragma unroll
        for (int j = 0; j < 4; ++j) s4[j] = f2b(w4[j]);
        *(short4v*)(Bs + r*64 + (((bgrp >> 1) ^ (r & 7))*8) + (bgrp & 1)*4) = s4;
      }
    }
    __syncthreads();

    #pragma unroll
    for (int ks = 0; ks < 2; ++ks) {
      short8 af[4], bfr[4];
      #pragma unroll
      for (int mi = 0; mi < 4; ++mi) {
        const int r = wm*64 + mi*16 + l15;
        const int p = (quad + ks*4) ^ (r & 7);
        af[mi] = *(const short8*)(As + r*64 + p*8);
      }
      #pragma unroll
      for (int ni = 0; ni < 4; ++ni) {
        const int r = wn*64 + ni*16 + l15;
        const int p = (quad + ks*4) ^ (r & 7);
        bfr[ni] = *(const short8*)(Bs + r*64 + p*8);
      }
      #pragma unroll
      for (int mi = 0; mi < 4; ++mi)
        #pragma unroll
        for (int ni = 0; ni < 4; ++ni)
          acc[mi][ni] = __builtin_amdgcn_mfma_f32_16x16x32_bf16(
              af[mi], bfr[ni], acc[mi][ni], 0, 0, 0);
    }
    __syncthreads();
  }

  #pragma unroll
  for (int mi = 0; mi < 4; ++mi) {
    #pragma unroll
    for (int reg = 0; reg < 4; ++reg) {
      const int row = bm0 + wm*64 + mi*16 + quad*4 + reg;
      #pragma unroll
      for (int ni = 0; ni < 4; ++ni) {
        const int col = bn0 + wn*64 + ni*16 + l15;
        const size_t off = (size_t)row*N + col;
        const float v = acc[mi][ni][reg];
        if (EPI == 0)      ((short*)C)[off] = f2b(v);
        else if (EPI == 1) ((float*)C)[off] = b2f(((const short*)RES)[off]) + v;
        else               ((float*)C)[off] = ((const float*)RES)[off] + v;
      }
    }
  }
}

// ---------------------------------------------------------------------------
// Fused QKV GEMM: one 512-block dispatch (grid 16 x 32) instead of three
// (k/v grids were half-idle).  N-region routing is block-uniform: bn0 spans
// 128 cols entirely inside one of {q: [0,2048), k: [2048,3072), v: [3072,4096)}.
// Same verified gemm_bt body (128x128 tile, BK=64, XOR chunk swizzle).
// ---------------------------------------------------------------------------
__global__ __launch_bounds__(256)
void gemm_qkv(const short* __restrict__ A,
              const short* __restrict__ Bq, const short* __restrict__ Bk,
              const short* __restrict__ Bv,
              short* __restrict__ q, short* __restrict__ k, short* __restrict__ v)
{
  __shared__ __attribute__((aligned(16))) short As[128*64];
  __shared__ __attribute__((aligned(16))) short Bs[128*64];

  const int tid = threadIdx.x;
  const int wv = tid >> 6, ln = tid & 63;
  const int wm = wv >> 1, wn = wv & 1;
  const int l15 = ln & 15, quad = ln >> 4;
  const int bm0 = blockIdx.x * 128, bn0 = blockIdx.y * 128;

  // block-uniform routing
  const short* Bp; short* C; int ldc, cb0;
  if (bn0 < 2048)      { Bp = Bq + (size_t)bn0*HIDN;        C = q; ldc = 2048; cb0 = bn0; }
  else if (bn0 < 3072) { Bp = Bk + (size_t)(bn0-2048)*HIDN; C = k; ldc = 1024; cb0 = bn0-2048; }
  else                 { Bp = Bv + (size_t)(bn0-3072)*HIDN; C = v; ldc = 1024; cb0 = bn0-3072; }

  f32x4 acc[4][4];
  #pragma unroll
  for (int i = 0; i < 4; ++i)
    #pragma unroll
    for (int j = 0; j < 4; ++j) acc[i][j] = (f32x4){0.f,0.f,0.f,0.f};

  const int srow = wv*32 + (ln >> 3);
  const int schk = ln & 7;

  for (int kt = 0; kt < HIDN; kt += 64) {
    #pragma unroll
    for (int i = 0; i < 4; ++i) {
      const int r = srow + i*8;
      const int g = schk ^ (r & 7);
      gll16(A + (size_t)(bm0 + r)*HIDN + kt + g*8,
            (char*)As + (wv*32 + i*8)*128);
      gll16(Bp + (size_t)r*HIDN + kt + g*8,
            (char*)Bs + (wv*32 + i*8)*128);
    }
    __syncthreads();

    #pragma unroll
    for (int ks = 0; ks < 2; ++ks) {
      short8 af[4], bfr[4];
      #pragma unroll
      for (int mi = 0; mi < 4; ++mi) {
        const int r = wm*64 + mi*16 + l15;
        const int p = (quad + ks*4) ^ (r & 7);
        af[mi] = *(const short8*)(As + r*64 + p*8);
      }
      #pragma unroll
      for (int ni = 0; ni < 4; ++ni) {
        const int r = wn*64 + ni*16 + l15;
        const int p = (quad + ks*4) ^ (r & 7);
        bfr[ni] = *(const short8*)(Bs + r*64 + p*8);
      }
      #pragma unroll
      for (int mi = 0; mi < 4; ++mi)
        #pragma unroll
        for (int ni = 0; ni < 4; ++ni)
          acc[mi][ni] = __builtin_amdgcn_mfma_f32_16x16x32_bf16(
              af[mi], bfr[ni], acc[mi][ni], 0, 0, 0);
    }
    __syncthreads();
  }

  #pragma unroll
  for (int mi = 0; mi < 4; ++mi) {
    #pragma unroll
    for (int reg = 0; reg < 4; ++reg) {
      const int row = bm0 + wm*64 + mi*16 + quad*4 + reg;
      #pragma unroll
      for (int ni = 0; ni < 4; ++ni) {
        const int col = cb0 + wn*64 + ni*16 + l15;
        C[(size_t)row*ldc + col] = f2b(acc[mi][ni][reg]);
      }
    }
  }
}

// ---------------------------------------------------------------------------
// 256x256 8-phase pipelined GEMM (T1+T2+T3+T4+T5).  C = A @ B^T, bf16 in,
// fp32 accum.  (unchanged structure; see round-1 comments for the schedule &
// vmcnt invariants.)
// EPI: 0 = bf16 store; 4 = fp32 partial store at z*(2048*2048) (split-K,
// reduced later by reduce_transpose -- replaces the atomicAdd variant).
// ---------------------------------------------------------------------------
#define BAR256()   do { __builtin_amdgcn_s_barrier();                      \
                        __builtin_amdgcn_sched_barrier(0); } while (0)
#define LGKM0()    do { asm volatile("s_waitcnt lgkmcnt(0)" ::: "memory"); \
                        __builtin_amdgcn_sched_barrier(0); } while (0)
#define VMC4()     do { asm volatile("s_waitcnt vmcnt(4)" ::: "memory");   \
                        __builtin_amdgcn_sched_barrier(0); } while (0)

template<int EPI>
__global__ __launch_bounds__(512, 2)
void gemm256(const short* __restrict__ A, int lda,
             const short* __restrict__ B, int ldb,
             void* __restrict__ C, int N, int Ko)
{
  __shared__ __attribute__((aligned(16))) char L[131072];

  const int tid = threadIdx.x;
  const int wv = tid >> 6, ln = tid & 63;
  const int wm = wv >> 2, wn = wv & 3;
  const int l15 = ln & 15, quad = ln >> 4;

  int bx, by;
  {
    const int nwg  = gridDim.x * gridDim.y;
    const int orig = blockIdx.y * gridDim.x + blockIdx.x;
    const int wg   = (orig & 7) * (nwg >> 3) + (orig >> 3);
    bx = wg % gridDim.x;
    by = wg / gridDim.x;
  }
  const int bm0 = bx * 256, bn0 = by * 256;
  const int k0  = blockIdx.z * Ko;

  const int srow = wv*8 + (ln >> 3);
  const int g8   = ((ln & 7) ^ ((ln >> 3) & 7)) * 8;
  const short* Ab = A + (size_t)bm0 * lda + k0 + g8;
  const short* Bb = B + (size_t)bn0 * ldb + k0 + g8;

  const int aro = l15 * 128;
  const int p0  = ((quad    ) ^ (l15 & 7)) * 16;
  const int p1  = ((quad + 4) ^ (l15 & 7)) * 16;

  f32x4 acc[8][4];
  #pragma unroll
  for (int i = 0; i < 8; ++i)
    #pragma unroll
    for (int j = 0; j < 4; ++j) acc[i][j] = (f32x4){0.f,0.f,0.f,0.f};

  short8 af[4][2], bf0[2][2], bf1[2][2];

  const int NT = Ko >> 6;
  const int NI = NT >> 1;

#define STG(base, ld, s, h, t, isB)                                          \
  { char* r_ = L + (isB)*65536 + ((s)*2 + (h))*16384 + wv*1024;              \
    _Pragma("unroll")                                                        \
    for (int i_ = 0; i_ < 2; ++i_)                                           \
      gll16(base + (size_t)((h)*128 + i_*64 + srow)*(ld) + (size_t)(t)*64,   \
            r_ + i_*8192); }

#define LD_A(s, mh)                                                          \
  { const char* a_ = L + ((s)*2 + wm)*16384 + (mh)*8192 + aro;               \
    _Pragma("unroll")                                                        \
    for (int m_ = 0; m_ < 4; ++m_) {                                         \
      af[m_][0] = *(const short8*)(a_ + m_*2048 + p0);                       \
      af[m_][1] = *(const short8*)(a_ + m_*2048 + p1);                       \
    } }

#define LD_B(s, nh, bfv)                                                     \
  { const char* b_ = L + 65536 + ((s)*2 + (wn>>1))*16384 + (wn&1)*8192       \
                     + (nh)*4096 + aro;                                      \
    _Pragma("unroll")                                                        \
    for (int n_ = 0; n_ < 2; ++n_) {                                         \
      bfv[n_][0] = *(const short8*)(b_ + n_*2048 + p0);                      \
      bfv[n_][1] = *(const short8*)(b_ + n_*2048 + p1);                      \
    } }

#define MM_Q(mh, nh, bfv)                                                    \
  { __builtin_amdgcn_s_setprio(1);                                           \
    _Pragma("unroll")                                                        \
    for (int m_ = 0; m_ < 4; ++m_)                                           \
      _Pragma("unroll")                                                      \
      for (int n_ = 0; n_ < 2; ++n_) {                                       \
        acc[(mh)*4+m_][(nh)*2+n_] = __builtin_amdgcn_mfma_f32_16x16x32_bf16( \
            af[m_][0], bfv[n_][0], acc[(mh)*4+m_][(nh)*2+n_], 0, 0, 0);      \
        acc[(mh)*4+m_][(nh)*2+n_] = __builtin_amdgcn_mfma_f32_16x16x32_bf16( \
            af[m_][1], bfv[n_][1], acc[(mh)*4+m_][(nh)*2+n_], 0, 0, 0);      \
      }                                                                      \
    __builtin_amdgcn_s_setprio(0); }

  STG(Ab, lda, 0,0, 0, 0); STG(Ab, lda, 0,1, 0, 0);
  STG(Bb, ldb, 0,0, 0, 1); STG(Bb, ldb, 0,1, 0, 1);
  STG(Bb, ldb, 1,0, 1, 1); STG(Bb, ldb, 1,1, 1, 1);
  VMC4();
  BAR256();

  for (int it = 0; it < NI; ++it) {
    const int u   = it*2;
    const int tA1 = u + 1;
    const int t2  = (u+2 < NT) ? u+2 : NT-1;
    const int t3  = (u+3 < NT) ? u+3 : NT-1;

    LD_A(0,0); LD_B(0,0,bf0);
    STG(Ab, lda, 1,0, tA1, 0);
    BAR256(); LGKM0();
    MM_Q(0,0,bf0);
    BAR256();

    LD_B(0,1,bf1);
    STG(Ab, lda, 1,1, tA1, 0);
    BAR256(); LGKM0();
    MM_Q(0,1,bf1);
    BAR256();

    LD_A(0,1);
    STG(Bb, ldb, 0,0, t2, 1);
    BAR256(); LGKM0();
    MM_Q(1,0,bf0);
    BAR256();

    STG(Bb, ldb, 0,1, t2, 1);
    BAR256(); LGKM0();
    MM_Q(1,1,bf1);
    VMC4();
    BAR256();

    LD_A(1,0); LD_B(1,0,bf0);
    STG(Ab, lda, 0,0, t2, 0);
    BAR256(); LGKM0();
    MM_Q(0,0,bf0);
    BAR256();

    LD_B(1,1,bf1);
    STG(Ab, lda, 0,1, t2, 0);
    BAR256(); LGKM0();
    MM_Q(0,1,bf1);
    BAR256();

    LD_A(1,1);
    STG(Bb, ldb, 1,0, t3, 1);
    BAR256(); LGKM0();
    MM_Q(1,0,bf0);
    BAR256();

    STG(Bb, ldb, 1,1, t3, 1);
    BAR256(); LGKM0();
    MM_Q(1,1,bf1);
    VMC4();
    BAR256();
  }

  #pragma unroll
  for (int mi = 0; mi < 8; ++mi) {
    #pragma unroll
    for (int reg = 0; reg < 4; ++reg) {
      const int row = bm0 + wm*128 + mi*16 + quad*4 + reg;
      #pragma unroll
      for (int ni = 0; ni < 4; ++ni) {
        const int col = bn0 + wn*64 + ni*16 + l15;
        const size_t off = (size_t)row*N + col;
        const float v = acc[mi][ni][reg];
        if (EPI == 0) ((short*)C)[off] = f2b(v);
        else          ((float*)C)[(size_t)blockIdx.z*(2048u*2048u) + off] = v;
      }
    }
  }
#undef STG
#undef LD_A
#undef LD_B
#undef MM_Q
}

// ---------------------------------------------------------------------------
// fp32 (rows_in, cols_in) -> bf16 (cols_in, rows_in)
// ---------------------------------------------------------------------------
__global__ __launch_bounds__(256)
void transpose_f2b(const float* __restrict__ in, short* __restrict__ out,
                   int rows_in, int cols_in)
{
  __shared__ float tile[64][65];
  const int c0 = blockIdx.x*64, r0 = blockIdx.y*64;
  const int tx = threadIdx.x & 63, ty = threadIdx.x >> 6;
  #pragma unroll
  for (int i = 0; i < 16; ++i) {
    const int r = ty + i*4;
    tile[r][tx] = in[(size_t)(r0+r)*cols_in + c0 + tx];
  }
  __syncthreads();
  #pragma unroll
  for (int i = 0; i < 16; ++i) {
    const int r = ty + i*4;
    out[(size_t)(c0+r)*rows_in + r0 + tx] = f2b(tile[tx][r]);
  }
}

// ---------------------------------------------------------------------------
// final epilogue: out[h][t] = hid[t][h] + sum_z part[z][t][h]   (fp32)
// fuses the split-K reduce of the down-GEMM with the output transpose.
// ---------------------------------------------------------------------------
__global__ __launch_bounds__(256)
void reduce_transpose(const float* __restrict__ hid, const float* __restrict__ part,
                      float* __restrict__ out)
{
  __shared__ float tile[64][65];
  const int c0 = blockIdx.x*64, r0 = blockIdx.y*64;   // c: HIDN, r: TSEQ
  const int tx = threadIdx.x & 63, ty = threadIdx.x >> 6;
  #pragma unroll
  for (int i = 0; i < 16; ++i) {
    const int r = ty + i*4;
    const size_t off = (size_t)(r0+r)*HIDN + c0 + tx;
    tile[r][tx] = hid[off] + part[off] + part[off + 4194304u]
                + part[off + 2u*4194304u] + part[off + 3u*4194304u];
  }
  __syncthreads();
  #pragma unroll
  for (int i = 0; i < 16; ++i) {
    const int r = ty + i*4;
    out[(size_t)(c0+r)*TSEQ + r0 + tx] = tile[tx][r];
  }
}

// ---------------------------------------------------------------------------
// row RMSNorm over HID=2048. X bf16, W fp32, Y bf16.
// ---------------------------------------------------------------------------
__global__ __launch_bounds__(256)
void rmsnorm_b(const short* __restrict__ X, const float* __restrict__ W,
               short* __restrict__ Y)
{
  const int row = blockIdx.x, tid = threadIdx.x;
  const int wv = tid >> 6, ln = tid & 63;
  const size_t base = (size_t)row*HIDN + tid*8;
  short8 xv = *(const short8*)(X + base);
  float x[8];
  #pragma unroll
  for (int j = 0; j < 8; ++j) x[j] = b2f(xv[j]);
  float s = 0.f;
  #pragma unroll
  for (int j = 0; j < 8; ++j) s += x[j]*x[j];
  #pragma unroll
  for (int off = 32; off; off >>= 1) s += __shfl_xor(s, off, 64);
  __shared__ float red[4];
  if (ln == 0) red[wv] = s;
  __syncthreads();
  const float tot = red[0]+red[1]+red[2]+red[3];
  const float r = rsqrtf(tot*(1.0f/HIDN) + EPS);
  f32x4 w0 = *(const f32x4*)(W + tid*8);
  f32x4 w1 = *(const f32x4*)(W + tid*8 + 4);
  short8 y;
  #pragma unroll
  for (int j = 0; j < 4; ++j) y[j]   = f2b(x[j]*r*w0[j]);
  #pragma unroll
  for (int j = 0; j < 4; ++j) y[j+4] = f2b(x[j+4]*r*w1[j]);
  *(short8*)(Y + base) = y;
}

// X fp32, W fp32, Y bf16
__global__ __launch_bounds__(256)
void rmsnorm_f(const float* __restrict__ X, const float* __restrict__ W,
               short* __restrict__ Y)
{
  const int row = blockIdx.x, tid = threadIdx.x;
  const int wv = tid >> 6, ln = tid & 63;
  const size_t base = (size_t)row*HIDN + tid*8;
  f32x4 a0 = *(const f32x4*)(X + base);
  f32x4 a1 = *(const f32x4*)(X + base + 4);
  float x[8] = {a0[0],a0[1],a0[2],a0[3],a1[0],a1[1],a1[2],a1[3]};
  float s = 0.f;
  #pragma unroll
  for (int j = 0; j < 8; ++j) s += x[j]*x[j];
  #pragma unroll
  for (int off = 32; off; off >>= 1) s += __shfl_xor(s, off, 64);
  __shared__ float red[4];
  if (ln == 0) red[wv] = s;
  __syncthreads();
  const float tot = red[0]+red[1]+red[2]+red[3];
  const float r = rsqrtf(tot*(1.0f/HIDN) + EPS);
  f32x4 w0 = *(const f32x4*)(W + tid*8);
  f32x4 w1 = *(const f32x4*)(W + tid*8 + 4);
  short8 y;
  #pragma unroll
  for (int j = 0; j < 4; ++j) y[j]   = f2b(x[j]*r*w0[j]);
  #pragma unroll
  for (int j = 0; j < 4; ++j) y[j+4] = f2b(x[j+4]*r*w1[j]);
  *(short8*)(Y + base) = y;
}

// ---------------------------------------------------------------------------
// fused per-head RMSNorm (D=128) + RoPE, in-place on bf16 q/k.
// ---------------------------------------------------------------------------
__global__ __launch_bounds__(64)
void qk_rms_rope(short* __restrict__ Qb, short* __restrict__ Kb,
                 const float* __restrict__ cosb, const float* __restrict__ sinb,
                 const float* __restrict__ qw, const float* __restrict__ kw)
{
  const int b = blockIdx.x;
  const int hi = b % (NHQ + NHKV);
  const int t  = b / (NHQ + NHKV);
  const int ln = threadIdx.x;
  short* row; const float* w;
  if (hi < NHQ) { row = Qb + (size_t)t*(NHQ*DH) + hi*DH; w = qw; }
  else          { row = Kb + (size_t)t*(NHKV*DH) + (hi-NHQ)*DH; w = kw; }
  float x0 = b2f(row[ln]), x1 = b2f(row[ln+64]);
  float s = x0*x0 + x1*x1;
  #pragma unroll
  for (int off = 32; off; off >>= 1) s += __shfl_xor(s, off, 64);
  const float r = rsqrtf(s*(1.0f/DH) + EPS);
  const float n0 = x0*r*w[ln];
  const float n1 = x1*r*w[ln+64];
  const float* cr = cosb + (size_t)t*DH;
  const float* sr = sinb + (size_t)t*DH;
  const float c0 = cr[ln], c1 = cr[ln+64];
  const float s0 = sr[ln], s1 = sr[ln+64];
  row[ln]    = f2b(n0*c0 - n1*s0);
  row[ln+64] = f2b(n1*c1 + n0*s1);
}

// ---------------------------------------------------------------------------
// causal flash attention, 16x16x32 MFMA.
// Round 4: double-buffered K/V pipeline, ONE barrier per KV-tile (was 3),
// T14 async-STAGE split: tile t+1's V global loads + K gll16 issue at the
// top of tile t (latency hidden under QK/softmax/PV); V ds_writes land after
// PV; the single end-of-tile __syncthreads (full vmcnt/lgkm drain) publishes
// both.  Race audit: every cross-wave write-to-buffer[nxt] is separated from
// the previous tile's reads-of-buffer[nxt] by that barrier.  Ps is per-wave
// private (no barrier needed; compiler tracks lgkm deps -- no inline asm).
// XOR chunk swizzles on Ks/Vt/Ps as verified in round 3 (conflicts 3.1e7 -> ~0).
// LDS: 2x16 + 2x16 + 8 = 72 KiB -> 2 blocks/CU.
// ---------------------------------------------------------------------------
__global__ __launch_bounds__(256)
void flash_attn(const short* __restrict__ Q, const short* __restrict__ Kb,
                const short* __restrict__ Vb, short* __restrict__ O)
{
  __shared__ __attribute__((aligned(16))) short Ks[2][64*128];
  __shared__ __attribute__((aligned(16))) short Vt[2][128*64];
  __shared__ __attribute__((aligned(16))) short Ps[4*16*64];

  const int tid = threadIdx.x, wv = tid >> 6, ln = tid & 63;
  const int l15 = ln & 15, quad = ln >> 4;
  const int l7 = l15 & 7;
  const int hh = blockIdx.y, kvh = hh >> 1;
  const int nbx = gridDim.x;
  const int bxr = blockIdx.x;
  const int bx  = (bxr & 1) ? (nbx - 1 - (bxr >> 1)) : (bxr >> 1);
  const int m0 = bx * 64;
  const int qm0 = m0 + wv*16;

  short8 qf[4];
  {
    const short* qb = Q + (size_t)(qm0 + l15)*(NHQ*DH) + hh*DH + quad*8;
    #pragma unroll
    for (int ks = 0; ks < 4; ++ks) qf[ks] = *(const short8*)(qb + ks*32);
  }

  f32x4 oa[8];
  #pragma unroll
  for (int i = 0; i < 8; ++i) oa[i] = (f32x4){0.f,0.f,0.f,0.f};
  float m_r[4] = {-1e30f,-1e30f,-1e30f,-1e30f};
  float l_r[4] = {0.f,0.f,0.f,0.f};

  const int vd = tid & 127, vsh = tid >> 7;
  short8 vreg[4];

  // prologue: stage tile 0 into buffer 0
  {
    #pragma unroll
    for (int cb = 0; cb < 4; ++cb)
      #pragma unroll
      for (int j = 0; j < 8; ++j)
        vreg[cb][j] = Vb[(size_t)(vsh*32 + cb*8 + j)*(NHKV*DH) + kvh*DH + vd];
    #pragma unroll
    for (int it = 0; it < 4; ++it) {
      const int r = (wv*4 + it)*4 + quad;
      const int g = l15 ^ (4*(it & 1) + quad);
      gll16(Kb + (size_t)r*(NHKV*DH) + kvh*DH + g*8,
            (char*)Ks[0] + (wv*4 + it)*1024);
    }
    #pragma unroll
    for (int cb = 0; cb < 4; ++cb)
      *(short8*)(Vt[0] + vd*64 + (((vsh*4 + cb) ^ (vd & 7))*8)) = vreg[cb];
    __syncthreads();
  }

  const int ntile = bx + 1;
  for (int t = 0; t < ntile; ++t) {
    const int cur = t & 1, nxt = cur ^ 1;
    const int s0 = t*64;
    const bool pf = (t + 1 < ntile);

    // prefetch tile t+1: V -> regs (waited only at the ds_write below),
    // K -> Ks[nxt] via gll16 (drained by the end-of-tile barrier)
    if (pf) {
      const int s1 = s0 + 64;
      #pragma unroll
      for (int cb = 0; cb < 4; ++cb)
        #pragma unroll
        for (int j = 0; j < 8; ++j)
          vreg[cb][j] = Vb[(size_t)(s1 + vsh*32 + cb*8 + j)*(NHKV*DH) + kvh*DH + vd];
      #pragma unroll
      for (int it = 0; it < 4; ++it) {
        const int r = (wv*4 + it)*4 + quad;
        const int g = l15 ^ (4*(it & 1) + quad);
        gll16(Kb + (size_t)(s1 + r)*(NHKV*DH) + kvh*DH + g*8,
              (char*)Ks[nxt] + (wv*4 + it)*1024);
      }
    }

    // QK^T from Ks[cur]
    f32x4 sc[4];
    #pragma unroll
    for (int ci = 0; ci < 4; ++ci) {
      f32x4 a = (f32x4){0.f,0.f,0.f,0.f};
      #pragma unroll
      for (int ks = 0; ks < 4; ++ks) {
        const int r = ci*16 + l15;
        const int p = (quad + ks*4) ^ l7;
        short8 kf = *(const short8*)(Ks[cur] + r*128 + p*8);
        a = __builtin_amdgcn_mfma_f32_16x16x32_bf16(qf[ks], kf, a, 0, 0, 0);
      }
      sc[ci] = a;
    }

    // online softmax
    float alpha[4];
    #pragma unroll
    for (int reg = 0; reg < 4; ++reg) {
      const int grow = qm0 + quad*4 + reg;
      float rmax = -1e30f;
      #pragma unroll
      for (int ci = 0; ci < 4; ++ci) {
        float vvv = sc[ci][reg]*SCL;
        const int gs = s0 + ci*16 + l15;
        vvv = (gs <= grow) ? vvv : -1e30f;
        sc[ci][reg] = vvv;
        rmax = fmaxf(rmax, vvv);
      }
      #pragma unroll
      for (int off = 1; off < 16; off <<= 1)
        rmax = fmaxf(rmax, __shfl_xor(rmax, off, 64));
      const float mn = fmaxf(m_r[reg], rmax);
      alpha[reg] = __expf(m_r[reg] - mn);
      m_r[reg] = mn;
      float rsum = 0.f;
      #pragma unroll
      for (int ci = 0; ci < 4; ++ci) {
        const float p = __expf(sc[ci][reg] - mn);
        sc[ci][reg] = p;
        rsum += p;
      }
      #pragma unroll
      for (int off = 1; off < 16; off <<= 1)
        rsum += __shfl_xor(rsum, off, 64);
      l_r[reg] = l_r[reg]*alpha[reg] + rsum;
    }
    #pragma unroll
    for (int ni = 0; ni < 8; ++ni)
      #pragma unroll
      for (int reg = 0; reg < 4; ++reg) oa[ni][reg] *= alpha[reg];

    // Ps write (per-wave private; swizzled)
    #pragma unroll
    for (int ci = 0; ci < 4; ++ci)
      #pragma unroll
      for (int reg = 0; reg < 4; ++reg) {
        const int row = quad*4 + reg;
        const int pc  = (ci*2 + (l15 >> 3)) ^ (row & 7);
        Ps[wv*1024 + row*64 + pc*8 + l7] = f2b(sc[ci][reg]);
      }

    // PV from Ps + Vt[cur]  (compiler inserts the lgkm wait for Ps)
    #pragma unroll
    for (int ks = 0; ks < 2; ++ks) {
      const int gp = quad + ks*4;
      const int pp = gp ^ l7;
      short8 pf8 = *(const short8*)(Ps + wv*1024 + l15*64 + pp*8);
      #pragma unroll
      for (int ni = 0; ni < 8; ++ni) {
        const int d = ni*16 + l15;
        short8 vf = *(const short8*)(Vt[cur] + d*64 + ((gp ^ l7)*8));
        oa[ni] = __builtin_amdgcn_mfma_f32_16x16x32_bf16(pf8, vf, oa[ni], 0, 0, 0);
      }
    }

    // land prefetched V into Vt[nxt] (tile t-1 readers passed last barrier)
    if (pf) {
      #pragma unroll
      for (int cb = 0; cb < 4; ++cb)
        *(short8*)(Vt[nxt] + vd*64 + (((vsh*4 + cb) ^ (vd & 7))*8)) = vreg[cb];
    }
    __syncthreads();  // publishes Ks[nxt] (vmcnt drain) + Vt[nxt] for tile t+1
  }

  #pragma unroll
  for (int reg = 0; reg < 4; ++reg) {
    const float inv = 1.0f / l_r[reg];
    const int row = qm0 + quad*4 + reg;
    #pragma unroll
    for (int ni = 0; ni < 8; ++ni)
      O[(size_t)row*(NHQ*DH) + hh*DH + ni*16 + l15] = f2b(oa[ni][reg]*inv);
  }
}

// ---------------------------------------------------------------------------
// gate half of gu (T, 2I)  <-  silu(gate) * up, in place (bf16)
// ---------------------------------------------------------------------------
__global__ __launch_bounds__(256)
void silu_mul(short* __restrict__ gu)
{
  const size_t idx = ((size_t)blockIdx.x*256 + threadIdx.x)*8;
  const size_t t = idx / IMID;
  const size_t i = idx % IMID;
  short* gp = gu + t*(2*IMID) + i;
  short8 g8 = *(const short8*)gp;
  short8 u8 = *(const short8*)(gp + IMID);
  short8 o;
  #pragma unroll
  for (int j = 0; j < 8; ++j) {
    const float g = b2f(g8[j]);
    const float u = b2f(u8[j]);
    const float sl = g / (1.f + __expf(-g));
    o[j] = f2b(sl*u);
  }
  *(short8*)gp = o;
}

// ---------------------------------------------------------------------------
extern "C" void kernel_launch(void* const* d_in, const int* in_sizes, int n_in,
                              void* d_out, int out_size, void* d_ws, size_t ws_size,
                              hipStream_t stream)
{
  const float* hc   = (const float*)d_in[0];
  const float* cosb = (const float*)d_in[1];
  const float* sinb = (const float*)d_in[2];
  const float* wq   = (const float*)d_in[5];
  const float* wk   = (const float*)d_in[6];
  const float* wvp  = (const float*)d_in[7];
  const float* wo   = (const float*)d_in[8];
  const float* wgu  = (const float*)d_in[9];
  const float* wdn  = (const float*)d_in[10];
  const float* iln  = (const float*)d_in[11];
  const float* pln  = (const float*)d_in[12];
  const float* qnw  = (const float*)d_in[13];
  const float* knw  = (const float*)d_in[14];

  // workspace map (192 MB peak):
  //  wgu_b 0-64 | wq_b 64-72 | wk_b 72-76 | wv_b 76-80 | wo_b 80-88
  //  xT 88-96 | h 96-104 | q 104-112 | k 112-116 | v 116-120 | ao 120-128
  //  hid (fp32) 104-120 (over q/k/v, dead after flash)
  //  h2 120-128 (over ao, dead after wo-gemm) | gu 128-192
  //  wdn_b 64-96 (over wq_b..xT, dead after wo-gemm)
  //  part (fp32, 4x16MB) 0-64 (over wgu_b, dead after gate_up)
  char* ws = (char*)d_ws;
  short* wgu_b = (short*)(ws);
  short* wq_b  = (short*)(ws + ((size_t)64 << 20));
  short* wk_b  = (short*)(ws + ((size_t)72 << 20));
  short* wv_b  = (short*)(ws + ((size_t)76 << 20));
  short* wo_b  = (short*)(ws + ((size_t)80 << 20));
  short* xT    = (short*)(ws + ((size_t)88 << 20));
  short* h     = (short*)(ws + ((size_t)96 << 20));
  short* q     = (short*)(ws + ((size_t)104 << 20));
  short* k     = (short*)(ws + ((size_t)112 << 20));
  short* v     = (short*)(ws + ((size_t)116 << 20));
  short* ao    = (short*)(ws + ((size_t)120 << 20));
  float* hid   = (float*)(ws + ((size_t)104 << 20));
  short* h2    = (short*)(ws + ((size_t)120 << 20));
  short* gu    = (short*)(ws + ((size_t)128 << 20));
  short* wdn_b = (short*)(ws + ((size_t)64 << 20));
  float* part  = (float*)(ws);

  const dim3 b256(256);
  const dim3 b512(512);

  // weight pre-convert (fp32 -> bf16)
  cvt_f2b<<<dim3(16384), b256, 0, stream>>>(wgu, wgu_b);  // 32M elems
  cvt_f2b<<<dim3(2048),  b256, 0, stream>>>(wq,  wq_b);   // 4M
  cvt_f2b<<<dim3(1024),  b256, 0, stream>>>(wk,  wk_b);   // 2M
  cvt_f2b<<<dim3(1024),  b256, 0, stream>>>(wvp, wv_b);   // 2M
  cvt_f2b<<<dim3(2048),  b256, 0, stream>>>(wo,  wo_b);   // 4M

  transpose_f2b<<<dim3(32,32), b256, 0, stream>>>(hc, xT, HIDN, TSEQ);
  rmsnorm_b<<<dim3(TSEQ), b256, 0, stream>>>(xT, iln, h);

  // fused QKV (grid 16x32 = 512 blocks, full GPU)
  gemm_qkv<<<dim3(16,32), b256, 0, stream>>>(h, wq_b, wk_b, wv_b, q, k, v);

  qk_rms_rope<<<dim3(TSEQ*(NHQ+NHKV)), dim3(64), 0, stream>>>(q, k, cosb, sinb, qnw, knw);

  flash_attn<<<dim3(TSEQ/64, NHQ), b256, 0, stream>>>(q, k, v, ao);

  gemm_bt<1,false><<<dim3(16,16), b256, 0, stream>>>(ao, 2048, wo_b, xT, hid, 2048, 2048);

  // w_down fp32 -> bf16 into the now-dead wq_b..xT region (16M elems)
  cvt_f2b<<<dim3(8192), b256, 0, stream>>>(wdn, wdn_b);

  rmsnorm_f<<<dim3(TSEQ), b256, 0, stream>>>(hid, pln, h2);

  // gate_up: (2048 x 16384 x 2048) on the 8-phase 256x256 kernel
  gemm256<0><<<dim3(8,64), b512, 0, stream>>>(h2, HIDN, wgu_b, HIDN, gu, 16384, 2048);
  silu_mul<<<dim3((TSEQ*IMID/8)/256), b256, 0, stream>>>(gu);
  // down: (2048 x 2048 x 8192), split-K x4 -> fp32 partials (over dead wgu_b)
  gemm256<4><<<dim3(8,8,4), b512, 0, stream>>>(gu, 2*IMID, wdn_b, IMID, part, 2048, 2048);

  // final: out = (hid + sum partials)^T
  reduce_transpose<<<dim3(32,32), b256, 0, stream>>>(hid, part, (float*)d_out);
}